// Round 2
// baseline (658.195 us; speedup 1.0000x reference)
//
#include <hip/hip_runtime.h>

using ushort  = unsigned short;
using bf16x8  = __attribute__((ext_vector_type(8))) __bf16;
using ushort8 = __attribute__((ext_vector_type(8))) unsigned short;
using f32x4   = __attribute__((ext_vector_type(4))) float;
using float4v = __attribute__((ext_vector_type(4))) float;

__device__ __forceinline__ float bf2f(ushort u) {
    union { unsigned int i; float f; } v; v.i = ((unsigned int)u) << 16; return v.f;
}
__device__ __forceinline__ ushort f2bf(float f) {
    union { float f; unsigned int i; } v; v.f = f;
    unsigned int r = v.i + 0x7FFFu + ((v.i >> 16) & 1u);
    return (ushort)(r >> 16);
}
__device__ __forceinline__ bf16x8 ld8(const ushort* p) {
    return __builtin_bit_cast(bf16x8, *(const ushort8*)p);
}
// async global->LDS, 16B per lane
__device__ __forceinline__ void glds16(const void* g, void* l) {
    __builtin_amdgcn_global_load_lds(
        (const __attribute__((address_space(1))) unsigned int*)g,
        (__attribute__((address_space(3))) unsigned int*)l, 16, 0, 0);
}

// ---------------------------------------------------------------------------
// Dtype sniffer: bf16 (flag=0) vs f32 (flag=1) storage, decided from `query`.
// ---------------------------------------------------------------------------
__global__ void sniff_kernel(const ushort* __restrict__ q, int* __restrict__ flag) {
    const int lane = threadIdx.x;              // 64 threads, 1 block
    float mx = 0.0f;
    for (int i = lane; i < 512; i += 64) {
        float v = bf2f(q[2 * i]);              // even halfword
        mx = fmaxf(mx, fabsf(v));
    }
#pragma unroll
    for (int off = 32; off >= 1; off >>= 1) mx = fmaxf(mx, __shfl_xor(mx, off, 64));
    if (lane == 0) *flag = (mx > 1.0e6f) ? 1 : 0;
}

// ---------------------------------------------------------------------------
// C[M=8192, N=1024] = A[M,K=1024] * W[N,K]^T + bias.
// 128x128 tile, BK=32, 4 waves, 4x4 fragments/wave, double-buffered LDS.
// XCD-aware block swizzle: each XCD gets 8 consecutive mb panels (A reuse in L2).
// EPI 0: none   EPI 1: RoPE   EPI 2: sigmoid
// ---------------------------------------------------------------------------
template<int EPI, int ABF16, int OUTF>
__global__ __launch_bounds__(256) void gemm_bt(
    const void* __restrict__ A, const void* __restrict__ W,
    const void* __restrict__ bias,
    const void* __restrict__ rc, const void* __restrict__ rs,
    void* __restrict__ C, const int* __restrict__ flag)
{
    constexpr int Kd = 1024, Nd = 1024;
    const bool f32m = (*flag != 0);
    const bool af32 = f32m && !ABF16;
    const bool wf32 = f32m;

    const int tid  = threadIdx.x;
    // XCD swizzle: 512 blocks = 8 XCD x 64; XCD x gets mb in [x*8, x*8+8), all nb
    const int swz  = (blockIdx.x & 7) * 64 + (blockIdx.x >> 3);
    const int nb   = swz & 7;           // N/128 = 8
    const int mb   = swz >> 3;          // M/128 = 64
    const int wave = tid >> 6;
    const int lane = tid & 63;
    const int quad = lane >> 4;
    const int l16  = lane & 15;
    const int wr   = wave >> 1;         // 2x2 wave grid, 64x64 per wave
    const int wc   = wave & 1;

    __shared__ __align__(16) ushort As[2][128 * 32];
    __shared__ __align__(16) ushort Bs[2][128 * 32];

    const int arow0 = mb * 128;
    const int brow0 = nb * 128;

    auto ldregs = [&](float4v r[4], const float* src, int row0, int k0) {
#pragma unroll
        for (int j = 0; j < 2; ++j) {
            const int c = j * 256 + tid;
            const float* gp = src + (size_t)(row0 + (c >> 2)) * Kd + k0 + (c & 3) * 8;
            r[2 * j]     = *(const float4v*)gp;
            r[2 * j + 1] = *(const float4v*)(gp + 4);
        }
    };
    auto cvtwr = [&](ushort* lds, const float4v r[4]) {
#pragma unroll
        for (int j = 0; j < 2; ++j) {
            const int c = j * 256 + tid;
            bf16x8 o;
#pragma unroll
            for (int i = 0; i < 4; ++i) {
                o[i]     = (__bf16)r[2 * j][i];
                o[i + 4] = (__bf16)r[2 * j + 1][i];
            }
            *(ushort8*)&lds[c * 8] = __builtin_bit_cast(ushort8, o);
        }
    };
    auto stage16 = [&](ushort* lds, const ushort* src, int row0, int k0) {
#pragma unroll
        for (int j = 0; j < 2; ++j) {
            const int c = j * 256 + tid;
            glds16(src + (size_t)(row0 + (c >> 2)) * Kd + k0 + (c & 3) * 8, &lds[c * 8]);
        }
    };

    {
        float4v t[4];
        if (af32) { ldregs(t, (const float*)A, arow0, 0); cvtwr(As[0], t); }
        else      stage16(As[0], (const ushort*)A, arow0, 0);
        if (wf32) { ldregs(t, (const float*)W, brow0, 0); cvtwr(Bs[0], t); }
        else      stage16(Bs[0], (const ushort*)W, brow0, 0);
    }

    f32x4 acc[4][4] = {};
    int cur = 0;
    for (int kt = 0; kt < 32; ++kt) {
        __syncthreads();
        const bool pf = (kt < 31);
        const int  kn = (kt + 1) * 32;
        float4v ra[4], rb[4];
        if (pf) {
            if (af32) ldregs(ra, (const float*)A, arow0, kn);
            else      stage16(As[cur ^ 1], (const ushort*)A, arow0, kn);
            if (wf32) ldregs(rb, (const float*)W, brow0, kn);
            else      stage16(Bs[cur ^ 1], (const ushort*)W, brow0, kn);
        }
        bf16x8 fa[4], fb[4];
#pragma unroll
        for (int mi = 0; mi < 4; ++mi)
            fa[mi] = ld8(&As[cur][(wr * 64 + mi * 16 + l16) * 32 + quad * 8]);
#pragma unroll
        for (int ni = 0; ni < 4; ++ni)
            fb[ni] = ld8(&Bs[cur][(wc * 64 + ni * 16 + l16) * 32 + quad * 8]);
#pragma unroll
        for (int mi = 0; mi < 4; ++mi)
#pragma unroll
            for (int ni = 0; ni < 4; ++ni)
                acc[mi][ni] = __builtin_amdgcn_mfma_f32_16x16x32_bf16(fa[mi], fb[ni], acc[mi][ni], 0, 0, 0);
        if (pf) {
            if (af32) cvtwr(As[cur ^ 1], ra);
            if (wf32) cvtwr(Bs[cur ^ 1], rb);
        }
        cur ^= 1;
    }

    const bool of32 = OUTF && f32m;
    const int colbase = nb * 128 + wc * 64;
    float bv[4];
#pragma unroll
    for (int ni = 0; ni < 4; ++ni) {
        const int cg = colbase + ni * 16 + l16;
        bv[ni] = wf32 ? ((const float*)bias)[cg] : bf2f(((const ushort*)bias)[cg]);
    }
    const int rowb = mb * 128 + wr * 64 + quad * 4;
#pragma unroll
    for (int mi = 0; mi < 4; ++mi) {
#pragma unroll
        for (int r = 0; r < 4; ++r) {
            const int rowg = rowb + mi * 16 + r;   // == b*1024 + pos
            float v[4];
#pragma unroll
            for (int ni = 0; ni < 4; ++ni) v[ni] = acc[mi][ni][r] + bv[ni];
            if constexpr (EPI == 1) {
#pragma unroll
                for (int t = 0; t < 2; ++t) {
                    const size_t ci = (size_t)rowg * 64 + t * 16 + l16;
                    const float c = f32m ? ((const float*)rc)[ci] : bf2f(((const ushort*)rc)[ci]);
                    const float s = f32m ? ((const float*)rs)[ci] : bf2f(((const ushort*)rs)[ci]);
                    const float x1 = v[t], x2 = v[t + 2];
                    v[t]     = x1 * c - x2 * s;
                    v[t + 2] = x2 * c + x1 * s;
                }
            } else if constexpr (EPI == 2) {
#pragma unroll
                for (int t = 0; t < 4; ++t) v[t] = 1.0f / (1.0f + __expf(-v[t]));
            }
#pragma unroll
            for (int ni = 0; ni < 4; ++ni) {
                const size_t idx = (size_t)rowg * Nd + colbase + ni * 16 + l16;
                if (of32) ((float*)C)[idx] = v[ni];
                else      ((ushort*)C)[idx] = f2bf(v[ni]);
            }
        }
    }
}

// ---------------------------------------------------------------------------
// Per-batch transpose: Vp[b*1024 + pos][col] -> Vt[b*1024 + col][pos]
// (col = h*64+hd). 64x64 tiles through padded LDS ([64][65] ushort: 2-way max).
// ---------------------------------------------------------------------------
__global__ __launch_bounds__(256) void transpose_vh(
    const ushort* __restrict__ Vp, ushort* __restrict__ Vt)
{
    const int bb = blockIdx.x >> 8;
    const int pr = (blockIdx.x >> 4) & 15;
    const int cr = blockIdx.x & 15;
    __shared__ ushort t[64 * 65];
    const int tid = threadIdx.x;
    {
        const int r = tid >> 3, c8 = (tid & 7) * 8;
#pragma unroll
        for (int hh = 0; hh < 2; ++hh) {
            const int rr = r + hh * 32;
            const ushort8 v = *(const ushort8*)(Vp + ((size_t)(bb * 1024 + pr * 64 + rr)) * 1024 + cr * 64 + c8);
#pragma unroll
            for (int i = 0; i < 8; ++i) t[rr * 65 + c8 + i] = v[i];
        }
    }
    __syncthreads();
    {
        const int c = tid >> 2, p0 = (tid & 3) * 16;
        ushort8 o0, o1;
#pragma unroll
        for (int i = 0; i < 8; ++i) {
            o0[i] = t[(p0 + i) * 65 + c];
            o1[i] = t[(p0 + 8 + i) * 65 + c];
        }
        ushort* dst = Vt + ((size_t)(bb * 1024 + cr * 64 + c)) * 1024 + pr * 64 + p0;
        *(ushort8*)dst       = o0;
        *(ushort8*)(dst + 8) = o1;
    }
}

// ---------------------------------------------------------------------------
// Flash attention v2: 4 waves/block, each wave owns 16 q-rows (64 q-rows/block).
// KVBLK=64. K read direct from global (L1/L2 shared across waves). V read as
// contiguous rows of pre-transposed Vt (no LDS for K/V, no scalar gathers).
// Per-wave private P-bounce LDS; ZERO __syncthreads. Gate fused in epilogue.
// ---------------------------------------------------------------------------
__global__ __launch_bounds__(256) void attn_kernel(
    const ushort* __restrict__ Qp, const ushort* __restrict__ Kp,
    const ushort* __restrict__ Vt, const ushort* __restrict__ G,
    const unsigned char* __restrict__ mask, ushort* __restrict__ O)
{
    // XCD swizzle: 2048 blocks = 8 XCD x 256; each XCD owns one batch b.
    const int swz = (blockIdx.x & 7) * 256 + (blockIdx.x >> 3);
    const int q64 = swz & 15;                // q-tile of 64 rows
    const int h   = (swz >> 4) & 15;
    const int b   = swz >> 8;
    const int wave = threadIdx.x >> 6;
    const int lane = threadIdx.x & 63;
    const int quad = lane >> 4;
    const int l16  = lane & 15;
    const size_t Dm = 1024;

    __shared__ __align__(16) ushort ldsP[4][16 * 72];   // per-wave P bounce

    const int q0 = q64 * 64 + wave * 16;
    const ushort* Qb = Qp + ((size_t)b * 1024 + q0 + l16) * Dm + h * 64 + quad * 8;
    const bf16x8 qa0 = ld8(Qb);
    const bf16x8 qa1 = ld8(Qb + 32);

    const ushort* Vbase = Vt + ((size_t)b * 1024 + h * 64) * 1024;  // row=hd, col=pos

    float m_r[4], l_r[4];
    f32x4 o[4] = {};
#pragma unroll
    for (int r = 0; r < 4; ++r) { m_r[r] = -3.0e38f; l_r[r] = 0.0f; }

    const float scale = 0.125f;   // 1/sqrt(64)
    for (int k0 = 0; k0 < 1024; k0 += 64) {
        // S = Q K^T : 4 col-tiles of 16 keys
        f32x4 s[4] = {};
#pragma unroll
        for (int ct = 0; ct < 4; ++ct) {
            const ushort* Kb = Kp + ((size_t)b * 1024 + k0 + ct * 16 + l16) * Dm + h * 64 + quad * 8;
            s[ct] = __builtin_amdgcn_mfma_f32_16x16x32_bf16(qa0, ld8(Kb),      s[ct], 0, 0, 0);
            s[ct] = __builtin_amdgcn_mfma_f32_16x16x32_bf16(qa1, ld8(Kb + 32), s[ct], 0, 0, 0);
        }
        // prefetch V B-fragments (contiguous Vt rows) -- latency hides under softmax
        bf16x8 vf[4][2];
#pragma unroll
        for (int t = 0; t < 4; ++t)
#pragma unroll
            for (int kk = 0; kk < 2; ++kk)
                vf[t][kk] = ld8(Vbase + (size_t)(t * 16 + l16) * 1024 + k0 + kk * 32 + quad * 8);
        bool msk[4];
#pragma unroll
        for (int ct = 0; ct < 4; ++ct)
            msk[ct] = mask[(size_t)b * 1024 + k0 + ct * 16 + l16] != 0;
        // online softmax per q-row (row = quad*4 + r; its 16 keys/tile live in the quad)
        float pr[4][4];
#pragma unroll
        for (int r = 0; r < 4; ++r) {
            float sv[4];
#pragma unroll
            for (int ct = 0; ct < 4; ++ct) sv[ct] = msk[ct] ? -1e30f : s[ct][r] * scale;
            float mx = fmaxf(fmaxf(sv[0], sv[1]), fmaxf(sv[2], sv[3]));
#pragma unroll
            for (int off = 8; off >= 1; off >>= 1) mx = fmaxf(mx, __shfl_xor(mx, off, 16));
            const float mnew  = fmaxf(m_r[r], mx);
            const float alpha = __expf(m_r[r] - mnew);
            float ps = 0.0f;
#pragma unroll
            for (int ct = 0; ct < 4; ++ct) { pr[r][ct] = __expf(sv[ct] - mnew); ps += pr[r][ct]; }
#pragma unroll
            for (int off = 8; off >= 1; off >>= 1) ps += __shfl_xor(ps, off, 16);
            l_r[r] = l_r[r] * alpha + ps;
            m_r[r] = mnew;
#pragma unroll
            for (int t = 0; t < 4; ++t) o[t][r] *= alpha;
        }
        // P -> A-layout bounce through per-wave LDS (stride 72 breaks pow2 banks)
#pragma unroll
        for (int r = 0; r < 4; ++r)
#pragma unroll
            for (int ct = 0; ct < 4; ++ct)
                ldsP[wave][(quad * 4 + r) * 72 + ct * 16 + l16] =
                    __builtin_bit_cast(ushort, (__bf16)pr[r][ct]);
        asm volatile("s_waitcnt lgkmcnt(0)" ::: "memory");
        __builtin_amdgcn_sched_barrier(0);
        const bf16x8 pa0 = ld8(&ldsP[wave][l16 * 72 + quad * 8]);
        const bf16x8 pa1 = ld8(&ldsP[wave][l16 * 72 + 32 + quad * 8]);
#pragma unroll
        for (int t = 0; t < 4; ++t) {
            o[t] = __builtin_amdgcn_mfma_f32_16x16x32_bf16(pa0, vf[t][0], o[t], 0, 0, 0);
            o[t] = __builtin_amdgcn_mfma_f32_16x16x32_bf16(pa1, vf[t][1], o[t], 0, 0, 0);
        }
    }
    // epilogue: normalize, gate, store bf16
    const int rowg0 = b * 1024 + q0 + quad * 4;
#pragma unroll
    for (int r = 0; r < 4; ++r) {
        const float inv = 1.0f / l_r[r];
#pragma unroll
        for (int t = 0; t < 4; ++t) {
            const size_t idx = (size_t)(rowg0 + r) * Dm + h * 64 + t * 16 + l16;
            O[idx] = f2bf(o[t][r] * inv * bf2f(G[idx]));
        }
    }
}

extern "C" void kernel_launch(void* const* d_in, const int* in_sizes, int n_in,
                              void* d_out, int out_size, void* d_ws, size_t ws_size,
                              hipStream_t stream)
{
    const void* query = d_in[0];
    const void* key   = d_in[1];
    const void* value = d_in[2];
    const void* Wq    = d_in[3];
    const void* bq    = d_in[4];
    const void* Wk    = d_in[5];
    const void* bk    = d_in[6];
    const void* Wv    = d_in[7];
    const void* bv    = d_in[8];
    const void* Wg    = d_in[9];
    const void* bg    = d_in[10];
    const void* Wo    = d_in[11];
    const void* bo    = d_in[12];
    const void* rc    = d_in[13];
    const void* rs    = d_in[14];
    const unsigned char* mask = (const unsigned char*)d_in[15];

    char* ws = (char*)d_ws;
    const size_t MB16 = (size_t)16 << 20;        // 8192*1024*2 bytes
    ushort* Qp = (ushort*)(ws);
    ushort* Kp = (ushort*)(ws + 1 * MB16);
    ushort* Vp = (ushort*)(ws + 2 * MB16);
    ushort* Gt = (ushort*)(ws + 3 * MB16);
    ushort* Vt = (ushort*)(ws + 4 * MB16);
    ushort* Ag = (ushort*)(ws + 2 * MB16);       // alias Vp: dead after transpose
    int*  flag = (int*)(ws + 5 * MB16);

    const dim3 gb(512), gt(256);
    hipLaunchKernelGGL(sniff_kernel, dim3(1), dim3(64), 0, stream, (const ushort*)query, flag);

    hipLaunchKernelGGL((gemm_bt<1,0,0>), gb, gt, 0, stream, query, Wq, bq, rc, rs, Qp, flag);
    hipLaunchKernelGGL((gemm_bt<1,0,0>), gb, gt, 0, stream, key,   Wk, bk, rc, rs, Kp, flag);
    hipLaunchKernelGGL((gemm_bt<0,0,0>), gb, gt, 0, stream, value, Wv, bv, rc, rs, Vp, flag);
    hipLaunchKernelGGL((gemm_bt<2,0,0>), gb, gt, 0, stream, query, Wg, bg, rc, rs, Gt, flag);

    hipLaunchKernelGGL(transpose_vh, dim3(2048), dim3(256), 0, stream, Vp, Vt);
    hipLaunchKernelGGL(attn_kernel,  dim3(2048), dim3(256), 0, stream, Qp, Kp, Vt, Gt, mask, Ag);

    // final projection: A (=Ag) is always bf16 workspace; W/bias + output follow mode
    hipLaunchKernelGGL((gemm_bt<0,1,1>), gb, gt, 0, stream, Ag, Wo, bo, rc, rs, d_out, flag);
}

// Round 3
// 621.355 us; speedup vs baseline: 1.0593x; 1.0593x over previous
//
#include <hip/hip_runtime.h>

using ushort  = unsigned short;
using bf16x8  = __attribute__((ext_vector_type(8))) __bf16;
using ushort8 = __attribute__((ext_vector_type(8))) unsigned short;
using f32x4   = __attribute__((ext_vector_type(4))) float;
using float4v = __attribute__((ext_vector_type(4))) float;

__device__ __forceinline__ float bf2f(ushort u) {
    union { unsigned int i; float f; } v; v.i = ((unsigned int)u) << 16; return v.f;
}
__device__ __forceinline__ ushort f2bf(float f) {
    union { float f; unsigned int i; } v; v.f = f;
    unsigned int r = v.i + 0x7FFFu + ((v.i >> 16) & 1u);
    return (ushort)(r >> 16);
}
__device__ __forceinline__ bf16x8 ld8(const ushort* p) {
    return __builtin_bit_cast(bf16x8, *(const ushort8*)p);
}
// async global->LDS, 16B per lane
__device__ __forceinline__ void glds16(const void* g, void* l) {
    __builtin_amdgcn_global_load_lds(
        (const __attribute__((address_space(1))) unsigned int*)g,
        (__attribute__((address_space(3))) unsigned int*)l, 16, 0, 0);
}

// ---------------------------------------------------------------------------
// Dtype sniffer: bf16 (flag=0) vs f32 (flag=1) storage, decided from `query`.
// ---------------------------------------------------------------------------
__global__ void sniff_kernel(const ushort* __restrict__ q, int* __restrict__ flag) {
    const int lane = threadIdx.x;              // 64 threads, 1 block
    float mx = 0.0f;
    for (int i = lane; i < 512; i += 64) {
        float v = bf2f(q[2 * i]);              // even halfword
        mx = fmaxf(mx, fabsf(v));
    }
#pragma unroll
    for (int off = 32; off >= 1; off >>= 1) mx = fmaxf(mx, __shfl_xor(mx, off, 64));
    if (lane == 0) *flag = (mx > 1.0e6f) ? 1 : 0;
}

// ---------------------------------------------------------------------------
// C[M=8192, N=1024] = A[M,K=1024] * W[N,K]^T + bias.
// 128x128 tile, BK=32, 4 waves, 4x4 fragments/wave, double-buffered LDS.
// XCD-aware block swizzle. EPI 0: none  1: RoPE  2: sigmoid
// ---------------------------------------------------------------------------
template<int EPI, int ABF16, int OUTF>
__global__ __launch_bounds__(256) void gemm_bt(
    const void* __restrict__ A, const void* __restrict__ W,
    const void* __restrict__ bias,
    const void* __restrict__ rc, const void* __restrict__ rs,
    void* __restrict__ C, const int* __restrict__ flag)
{
    constexpr int Kd = 1024, Nd = 1024;
    const bool f32m = (*flag != 0);
    const bool af32 = f32m && !ABF16;
    const bool wf32 = f32m;

    const int tid  = threadIdx.x;
    // XCD swizzle: 512 blocks = 8 XCD x 64; XCD x gets mb in [x*8, x*8+8), all nb
    const int swz  = (blockIdx.x & 7) * 64 + (blockIdx.x >> 3);
    const int nb   = swz & 7;           // N/128 = 8
    const int mb   = swz >> 3;          // M/128 = 64
    const int wave = tid >> 6;
    const int lane = tid & 63;
    const int quad = lane >> 4;
    const int l16  = lane & 15;
    const int wr   = wave >> 1;         // 2x2 wave grid, 64x64 per wave
    const int wc   = wave & 1;

    __shared__ __align__(16) ushort As[2][128 * 32];
    __shared__ __align__(16) ushort Bs[2][128 * 32];

    const int arow0 = mb * 128;
    const int brow0 = nb * 128;

    auto ldregs = [&](float4v r[4], const float* src, int row0, int k0) {
#pragma unroll
        for (int j = 0; j < 2; ++j) {
            const int c = j * 256 + tid;
            const float* gp = src + (size_t)(row0 + (c >> 2)) * Kd + k0 + (c & 3) * 8;
            r[2 * j]     = *(const float4v*)gp;
            r[2 * j + 1] = *(const float4v*)(gp + 4);
        }
    };
    auto cvtwr = [&](ushort* lds, const float4v r[4]) {
#pragma unroll
        for (int j = 0; j < 2; ++j) {
            const int c = j * 256 + tid;
            bf16x8 o;
#pragma unroll
            for (int i = 0; i < 4; ++i) {
                o[i]     = (__bf16)r[2 * j][i];
                o[i + 4] = (__bf16)r[2 * j + 1][i];
            }
            *(ushort8*)&lds[c * 8] = __builtin_bit_cast(ushort8, o);
        }
    };
    auto stage16 = [&](ushort* lds, const ushort* src, int row0, int k0) {
#pragma unroll
        for (int j = 0; j < 2; ++j) {
            const int c = j * 256 + tid;
            glds16(src + (size_t)(row0 + (c >> 2)) * Kd + k0 + (c & 3) * 8, &lds[c * 8]);
        }
    };

    {
        float4v t[4];
        if (af32) { ldregs(t, (const float*)A, arow0, 0); cvtwr(As[0], t); }
        else      stage16(As[0], (const ushort*)A, arow0, 0);
        if (wf32) { ldregs(t, (const float*)W, brow0, 0); cvtwr(Bs[0], t); }
        else      stage16(Bs[0], (const ushort*)W, brow0, 0);
    }

    f32x4 acc[4][4] = {};
    int cur = 0;
    for (int kt = 0; kt < 32; ++kt) {
        __syncthreads();
        const bool pf = (kt < 31);
        const int  kn = (kt + 1) * 32;
        float4v ra[4], rb[4];
        if (pf) {
            if (af32) ldregs(ra, (const float*)A, arow0, kn);
            else      stage16(As[cur ^ 1], (const ushort*)A, arow0, kn);
            if (wf32) ldregs(rb, (const float*)W, brow0, kn);
            else      stage16(Bs[cur ^ 1], (const ushort*)W, brow0, kn);
        }
        bf16x8 fa[4], fb[4];
#pragma unroll
        for (int mi = 0; mi < 4; ++mi)
            fa[mi] = ld8(&As[cur][(wr * 64 + mi * 16 + l16) * 32 + quad * 8]);
#pragma unroll
        for (int ni = 0; ni < 4; ++ni)
            fb[ni] = ld8(&Bs[cur][(wc * 64 + ni * 16 + l16) * 32 + quad * 8]);
#pragma unroll
        for (int mi = 0; mi < 4; ++mi)
#pragma unroll
            for (int ni = 0; ni < 4; ++ni)
                acc[mi][ni] = __builtin_amdgcn_mfma_f32_16x16x32_bf16(fa[mi], fb[ni], acc[mi][ni], 0, 0, 0);
        if (pf) {
            if (af32) cvtwr(As[cur ^ 1], ra);
            if (wf32) cvtwr(Bs[cur ^ 1], rb);
        }
        cur ^= 1;
    }

    const bool of32 = OUTF && f32m;
    const int colbase = nb * 128 + wc * 64;
    float bv[4];
#pragma unroll
    for (int ni = 0; ni < 4; ++ni) {
        const int cg = colbase + ni * 16 + l16;
        bv[ni] = wf32 ? ((const float*)bias)[cg] : bf2f(((const ushort*)bias)[cg]);
    }
    const int rowb = mb * 128 + wr * 64 + quad * 4;
#pragma unroll
    for (int mi = 0; mi < 4; ++mi) {
#pragma unroll
        for (int r = 0; r < 4; ++r) {
            const int rowg = rowb + mi * 16 + r;   // == b*1024 + pos
            float v[4];
#pragma unroll
            for (int ni = 0; ni < 4; ++ni) v[ni] = acc[mi][ni][r] + bv[ni];
            if constexpr (EPI == 1) {
#pragma unroll
                for (int t = 0; t < 2; ++t) {
                    const size_t ci = (size_t)rowg * 64 + t * 16 + l16;
                    const float c = f32m ? ((const float*)rc)[ci] : bf2f(((const ushort*)rc)[ci]);
                    const float s = f32m ? ((const float*)rs)[ci] : bf2f(((const ushort*)rs)[ci]);
                    const float x1 = v[t], x2 = v[t + 2];
                    v[t]     = x1 * c - x2 * s;
                    v[t + 2] = x2 * c + x1 * s;
                }
            } else if constexpr (EPI == 2) {
#pragma unroll
                for (int t = 0; t < 4; ++t) v[t] = 1.0f / (1.0f + __expf(-v[t]));
            }
#pragma unroll
            for (int ni = 0; ni < 4; ++ni) {
                const size_t idx = (size_t)rowg * Nd + colbase + ni * 16 + l16;
                if (of32) ((float*)C)[idx] = v[ni];
                else      ((ushort*)C)[idx] = f2bf(v[ni]);
            }
        }
    }
}

// ---------------------------------------------------------------------------
// Per-batch transpose: Vp[b*1024 + pos][col] -> Vt[b*1024 + col][pos]
// 64x64 tiles through padded LDS.
// ---------------------------------------------------------------------------
__global__ __launch_bounds__(256) void transpose_vh(
    const ushort* __restrict__ Vp, ushort* __restrict__ Vt)
{
    const int bb = blockIdx.x >> 8;
    const int pr = (blockIdx.x >> 4) & 15;
    const int cr = blockIdx.x & 15;
    __shared__ ushort t[64 * 65];
    const int tid = threadIdx.x;
    {
        const int r = tid >> 3, c8 = (tid & 7) * 8;
#pragma unroll
        for (int hh = 0; hh < 2; ++hh) {
            const int rr = r + hh * 32;
            const ushort8 v = *(const ushort8*)(Vp + ((size_t)(bb * 1024 + pr * 64 + rr)) * 1024 + cr * 64 + c8);
#pragma unroll
            for (int i = 0; i < 8; ++i) t[rr * 65 + c8 + i] = v[i];
        }
    }
    __syncthreads();
    {
        const int c = tid >> 2, p0 = (tid & 3) * 16;
        ushort8 o0, o1;
#pragma unroll
        for (int i = 0; i < 8; ++i) {
            o0[i] = t[(p0 + i) * 65 + c];
            o1[i] = t[(p0 + 8 + i) * 65 + c];
        }
        ushort* dst = Vt + ((size_t)(bb * 1024 + cr * 64 + c)) * 1024 + pr * 64 + p0;
        *(ushort8*)dst       = o0;
        *(ushort8*)(dst + 8) = o1;
    }
}

// ---------------------------------------------------------------------------
// Flash attention v3: back to 1 independent wave per (b,h,16-row q-tile)
// (8192 x 64-thread blocks -- the high-occupancy grid), KVBLK=64.
// K read direct from global (L2-resident per XCD); V read as contiguous rows
// of pre-transposed Vt. Per-block private P-bounce LDS; no __syncthreads.
// Issue order per iter: K loads -> QK^T -> V loads -> softmax -> P bounce -> PV
// so V latency hides under softmax+bounce and QK^T only waits on K.
// ---------------------------------------------------------------------------
__global__ __launch_bounds__(64) void attn_kernel(
    const ushort* __restrict__ Qp, const ushort* __restrict__ Kp,
    const ushort* __restrict__ Vt, const ushort* __restrict__ G,
    const unsigned char* __restrict__ mask, ushort* __restrict__ O)
{
    // XCD swizzle: 8192 blocks = 8 XCD x 1024; XCD x owns batch x entirely
    // (K+V working set for one batch/head group stays in that XCD's 4MB L2).
    const int swz = (blockIdx.x & 7) * 1024 + (blockIdx.x >> 3);
    const int qt = swz & 63;                 // 16-row q-tile
    const int h  = (swz >> 6) & 15;
    const int b  = swz >> 10;
    const int lane = threadIdx.x;
    const int quad = lane >> 4;
    const int l16  = lane & 15;
    const size_t Dm = 1024;

    __shared__ __align__(16) ushort ldsP[16 * 72];

    const ushort* Qb = Qp + ((size_t)b * 1024 + qt * 16 + l16) * Dm + h * 64 + quad * 8;
    const bf16x8 qa0 = ld8(Qb);
    const bf16x8 qa1 = ld8(Qb + 32);

    const ushort* Kbase = Kp + (size_t)b * 1024 * Dm + h * 64;
    const ushort* Vbase = Vt + ((size_t)b * 1024 + h * 64) * 1024;  // row=hd, col=pos
    const unsigned char* mrow = mask + (size_t)b * 1024;

    float m_r[4], l_r[4];
    f32x4 o[4] = {};
#pragma unroll
    for (int r = 0; r < 4; ++r) { m_r[r] = -3.0e38f; l_r[r] = 0.0f; }

    const float scale = 0.125f;   // 1/sqrt(64)
    for (int k0 = 0; k0 < 1024; k0 += 64) {
        // --- K loads, then QK^T (4 col-tiles of 16 keys, K-dim 64) ---
        bf16x8 kf[4][2];
#pragma unroll
        for (int ct = 0; ct < 4; ++ct) {
            const ushort* Kb = Kbase + (size_t)(k0 + ct * 16 + l16) * Dm + quad * 8;
            kf[ct][0] = ld8(Kb);
            kf[ct][1] = ld8(Kb + 32);
        }
        f32x4 s[4] = {};
        __builtin_amdgcn_s_setprio(1);
#pragma unroll
        for (int ct = 0; ct < 4; ++ct) {
            s[ct] = __builtin_amdgcn_mfma_f32_16x16x32_bf16(qa0, kf[ct][0], s[ct], 0, 0, 0);
            s[ct] = __builtin_amdgcn_mfma_f32_16x16x32_bf16(qa1, kf[ct][1], s[ct], 0, 0, 0);
        }
        __builtin_amdgcn_s_setprio(0);
        // --- V loads (contiguous Vt rows); consumed after softmax+bounce ---
        bf16x8 vf[4][2];
#pragma unroll
        for (int t = 0; t < 4; ++t)
#pragma unroll
            for (int kk = 0; kk < 2; ++kk)
                vf[t][kk] = ld8(Vbase + (size_t)(t * 16 + l16) * 1024 + k0 + kk * 32 + quad * 8);
        bool msk[4];
#pragma unroll
        for (int ct = 0; ct < 4; ++ct) msk[ct] = mrow[k0 + ct * 16 + l16] != 0;
        // --- online softmax per q-row (row = quad*4 + r) ---
        float pr[4][4];
#pragma unroll
        for (int r = 0; r < 4; ++r) {
            float sv[4];
#pragma unroll
            for (int ct = 0; ct < 4; ++ct) sv[ct] = msk[ct] ? -1e30f : s[ct][r] * scale;
            float mx = fmaxf(fmaxf(sv[0], sv[1]), fmaxf(sv[2], sv[3]));
#pragma unroll
            for (int off = 8; off >= 1; off >>= 1) mx = fmaxf(mx, __shfl_xor(mx, off, 16));
            const float mnew  = fmaxf(m_r[r], mx);
            const float alpha = __expf(m_r[r] - mnew);
            float ps = 0.0f;
#pragma unroll
            for (int ct = 0; ct < 4; ++ct) { pr[r][ct] = __expf(sv[ct] - mnew); ps += pr[r][ct]; }
#pragma unroll
            for (int off = 8; off >= 1; off >>= 1) ps += __shfl_xor(ps, off, 16);
            l_r[r] = l_r[r] * alpha + ps;
            m_r[r] = mnew;
#pragma unroll
            for (int t = 0; t < 4; ++t) o[t][r] *= alpha;
        }
        // --- P -> A-layout bounce (wave-private LDS, stride 72) ---
#pragma unroll
        for (int r = 0; r < 4; ++r)
#pragma unroll
            for (int ct = 0; ct < 4; ++ct)
                ldsP[(quad * 4 + r) * 72 + ct * 16 + l16] =
                    __builtin_bit_cast(ushort, (__bf16)pr[r][ct]);
        asm volatile("s_waitcnt lgkmcnt(0)" ::: "memory");
        __builtin_amdgcn_sched_barrier(0);
        const bf16x8 pa0 = ld8(&ldsP[l16 * 72 + quad * 8]);
        const bf16x8 pa1 = ld8(&ldsP[l16 * 72 + 32 + quad * 8]);
        __builtin_amdgcn_s_setprio(1);
#pragma unroll
        for (int t = 0; t < 4; ++t) {
            o[t] = __builtin_amdgcn_mfma_f32_16x16x32_bf16(pa0, vf[t][0], o[t], 0, 0, 0);
            o[t] = __builtin_amdgcn_mfma_f32_16x16x32_bf16(pa1, vf[t][1], o[t], 0, 0, 0);
        }
        __builtin_amdgcn_s_setprio(0);
    }
    // epilogue: normalize, gate, store bf16
    const int rowg0 = b * 1024 + qt * 16 + quad * 4;
#pragma unroll
    for (int r = 0; r < 4; ++r) {
        const float inv = 1.0f / l_r[r];
#pragma unroll
        for (int t = 0; t < 4; ++t) {
            const size_t idx = (size_t)(rowg0 + r) * Dm + h * 64 + t * 16 + l16;
            O[idx] = f2bf(o[t][r] * inv * bf2f(G[idx]));
        }
    }
}

extern "C" void kernel_launch(void* const* d_in, const int* in_sizes, int n_in,
                              void* d_out, int out_size, void* d_ws, size_t ws_size,
                              hipStream_t stream)
{
    const void* query = d_in[0];
    const void* key   = d_in[1];
    const void* value = d_in[2];
    const void* Wq    = d_in[3];
    const void* bq    = d_in[4];
    const void* Wk    = d_in[5];
    const void* bk    = d_in[6];
    const void* Wv    = d_in[7];
    const void* bv    = d_in[8];
    const void* Wg    = d_in[9];
    const void* bg    = d_in[10];
    const void* Wo    = d_in[11];
    const void* bo    = d_in[12];
    const void* rc    = d_in[13];
    const void* rs    = d_in[14];
    const unsigned char* mask = (const unsigned char*)d_in[15];

    char* ws = (char*)d_ws;
    const size_t MB16 = (size_t)16 << 20;        // 8192*1024*2 bytes
    ushort* Qp = (ushort*)(ws);
    ushort* Kp = (ushort*)(ws + 1 * MB16);
    ushort* Vp = (ushort*)(ws + 2 * MB16);
    ushort* Gt = (ushort*)(ws + 3 * MB16);
    ushort* Vt = (ushort*)(ws + 4 * MB16);
    ushort* Ag = (ushort*)(ws + 2 * MB16);       // alias Vp: dead after transpose
    int*  flag = (int*)(ws + 5 * MB16);

    const dim3 gb(512), gt(256);
    hipLaunchKernelGGL(sniff_kernel, dim3(1), dim3(64), 0, stream, (const ushort*)query, flag);

    hipLaunchKernelGGL((gemm_bt<1,0,0>), gb, gt, 0, stream, query, Wq, bq, rc, rs, Qp, flag);
    hipLaunchKernelGGL((gemm_bt<1,0,0>), gb, gt, 0, stream, key,   Wk, bk, rc, rs, Kp, flag);
    hipLaunchKernelGGL((gemm_bt<0,0,0>), gb, gt, 0, stream, value, Wv, bv, rc, rs, Vp, flag);
    hipLaunchKernelGGL((gemm_bt<2,0,0>), gb, gt, 0, stream, query, Wg, bg, rc, rs, Gt, flag);

    hipLaunchKernelGGL(transpose_vh, dim3(2048), dim3(256), 0, stream, Vp, Vt);
    hipLaunchKernelGGL(attn_kernel,  dim3(8192), dim3(64), 0, stream, Qp, Kp, Vt, Gt, mask, Ag);

    // final projection: A (=Ag) is always bf16 workspace; W/bias + output follow mode
    hipLaunchKernelGGL((gemm_bt<0,1,1>), gb, gt, 0, stream, Ag, Wo, bo, rc, rs, d_out, flag);
}

// Round 4
// 463.019 us; speedup vs baseline: 1.4215x; 1.3420x over previous
//
#include <hip/hip_runtime.h>

using ushort  = unsigned short;
using bf16x8  = __attribute__((ext_vector_type(8))) __bf16;
using ushort8 = __attribute__((ext_vector_type(8))) unsigned short;
using f32x4   = __attribute__((ext_vector_type(4))) float;
using float4v = __attribute__((ext_vector_type(4))) float;

__device__ __forceinline__ float bf2f(ushort u) {
    union { unsigned int i; float f; } v; v.i = ((unsigned int)u) << 16; return v.f;
}
__device__ __forceinline__ ushort f2bf(float f) {
    union { float f; unsigned int i; } v; v.f = f;
    unsigned int r = v.i + 0x7FFFu + ((v.i >> 16) & 1u);
    return (ushort)(r >> 16);
}
__device__ __forceinline__ bf16x8 ld8(const ushort* p) {
    return __builtin_bit_cast(bf16x8, *(const ushort8*)p);
}
// async global->LDS, 16B per lane (dest = wave-uniform base + lane*16)
__device__ __forceinline__ void glds16(const void* g, void* l) {
    __builtin_amdgcn_global_load_lds(
        (const __attribute__((address_space(1))) unsigned int*)g,
        (__attribute__((address_space(3))) unsigned int*)l, 16, 0, 0);
}

// ---------------------------------------------------------------------------
// Dtype sniffer: bf16 (flag=0) vs f32 (flag=1) storage, decided from `query`.
// ---------------------------------------------------------------------------
__global__ void sniff_kernel(const ushort* __restrict__ q, int* __restrict__ flag) {
    const int lane = threadIdx.x;              // 64 threads, 1 block
    float mx = 0.0f;
    for (int i = lane; i < 512; i += 64) {
        float v = bf2f(q[2 * i]);              // even halfword
        mx = fmaxf(mx, fabsf(v));
    }
#pragma unroll
    for (int off = 32; off >= 1; off >>= 1) mx = fmaxf(mx, __shfl_xor(mx, off, 64));
    if (lane == 0) *flag = (mx > 1.0e6f) ? 1 : 0;
}

// ---------------------------------------------------------------------------
// Convert-or-copy to bf16 workspace: f32 mode -> cvt, bf16 mode -> memcpy.
// n8 = element count / 8.
// ---------------------------------------------------------------------------
__global__ __launch_bounds__(256) void cvt_kernel(
    const void* __restrict__ src, ushort* __restrict__ dst, int n8,
    const int* __restrict__ flag)
{
    const bool f32m = (*flag != 0);
    const int stride = gridDim.x * 256;
    for (int i = blockIdx.x * 256 + threadIdx.x; i < n8; i += stride) {
        if (f32m) {
            const float4v a = ((const float4v*)src)[2 * i];
            const float4v b = ((const float4v*)src)[2 * i + 1];
            bf16x8 o;
#pragma unroll
            for (int j = 0; j < 4; ++j) { o[j] = (__bf16)a[j]; o[j + 4] = (__bf16)b[j]; }
            ((ushort8*)dst)[i] = __builtin_bit_cast(ushort8, o);
        } else {
            ((ushort8*)dst)[i] = ((const ushort8*)src)[i];
        }
    }
}

// ---------------------------------------------------------------------------
// C[M=8192, N=1024] = A[M,K=1024] * W[N,K]^T + bias.
// 128x128 tile, BK=32, 4 waves, 4x4 fragments/wave, double-buffered LDS.
// XCD-aware block swizzle. EPI 0: none  1: RoPE  2: sigmoid
// ABF16/WBF16: operand is always-bf16 (workspace) regardless of flag.
// ---------------------------------------------------------------------------
template<int EPI, int ABF16, int WBF16, int OUTF>
__global__ __launch_bounds__(256) void gemm_bt(
    const void* __restrict__ A, const void* __restrict__ W,
    const void* __restrict__ bias,
    const void* __restrict__ rc, const void* __restrict__ rs,
    void* __restrict__ C, const int* __restrict__ flag)
{
    constexpr int Kd = 1024, Nd = 1024;
    const bool f32m = (*flag != 0);
    const bool af32 = f32m && !ABF16;
    const bool wf32 = f32m && !WBF16;

    const int tid  = threadIdx.x;
    // XCD swizzle: 512 blocks = 8 XCD x 64; XCD x gets mb in [x*8, x*8+8), all nb
    const int swz  = (blockIdx.x & 7) * 64 + (blockIdx.x >> 3);
    const int nb   = swz & 7;           // N/128 = 8
    const int mb   = swz >> 3;          // M/128 = 64
    const int wave = tid >> 6;
    const int lane = tid & 63;
    const int quad = lane >> 4;
    const int l16  = lane & 15;
    const int wr   = wave >> 1;         // 2x2 wave grid, 64x64 per wave
    const int wc   = wave & 1;

    __shared__ __align__(16) ushort As[2][128 * 32];
    __shared__ __align__(16) ushort Bs[2][128 * 32];

    const int arow0 = mb * 128;
    const int brow0 = nb * 128;

    auto ldregs = [&](float4v r[4], const float* src, int row0, int k0) {
#pragma unroll
        for (int j = 0; j < 2; ++j) {
            const int c = j * 256 + tid;
            const float* gp = src + (size_t)(row0 + (c >> 2)) * Kd + k0 + (c & 3) * 8;
            r[2 * j]     = *(const float4v*)gp;
            r[2 * j + 1] = *(const float4v*)(gp + 4);
        }
    };
    auto cvtwr = [&](ushort* lds, const float4v r[4]) {
#pragma unroll
        for (int j = 0; j < 2; ++j) {
            const int c = j * 256 + tid;
            bf16x8 o;
#pragma unroll
            for (int i = 0; i < 4; ++i) {
                o[i]     = (__bf16)r[2 * j][i];
                o[i + 4] = (__bf16)r[2 * j + 1][i];
            }
            *(ushort8*)&lds[c * 8] = __builtin_bit_cast(ushort8, o);
        }
    };
    auto stage16 = [&](ushort* lds, const ushort* src, int row0, int k0) {
#pragma unroll
        for (int j = 0; j < 2; ++j) {
            const int c = j * 256 + tid;
            glds16(src + (size_t)(row0 + (c >> 2)) * Kd + k0 + (c & 3) * 8, &lds[c * 8]);
        }
    };

    {
        float4v t[4];
        if (af32) { ldregs(t, (const float*)A, arow0, 0); cvtwr(As[0], t); }
        else      stage16(As[0], (const ushort*)A, arow0, 0);
        if (wf32) { ldregs(t, (const float*)W, brow0, 0); cvtwr(Bs[0], t); }
        else      stage16(Bs[0], (const ushort*)W, brow0, 0);
    }

    f32x4 acc[4][4] = {};
    int cur = 0;
    for (int kt = 0; kt < 32; ++kt) {
        __syncthreads();
        const bool pf = (kt < 31);
        const int  kn = (kt + 1) * 32;
        float4v ra[4], rb[4];
        if (pf) {
            if (af32) ldregs(ra, (const float*)A, arow0, kn);
            else      stage16(As[cur ^ 1], (const ushort*)A, arow0, kn);
            if (wf32) ldregs(rb, (const float*)W, brow0, kn);
            else      stage16(Bs[cur ^ 1], (const ushort*)W, brow0, kn);
        }
        bf16x8 fa[4], fb[4];
#pragma unroll
        for (int mi = 0; mi < 4; ++mi)
            fa[mi] = ld8(&As[cur][(wr * 64 + mi * 16 + l16) * 32 + quad * 8]);
#pragma unroll
        for (int ni = 0; ni < 4; ++ni)
            fb[ni] = ld8(&Bs[cur][(wc * 64 + ni * 16 + l16) * 32 + quad * 8]);
#pragma unroll
        for (int mi = 0; mi < 4; ++mi)
#pragma unroll
            for (int ni = 0; ni < 4; ++ni)
                acc[mi][ni] = __builtin_amdgcn_mfma_f32_16x16x32_bf16(fa[mi], fb[ni], acc[mi][ni], 0, 0, 0);
        if (pf) {
            if (af32) cvtwr(As[cur ^ 1], ra);
            if (wf32) cvtwr(Bs[cur ^ 1], rb);
        }
        cur ^= 1;
    }

    const bool of32 = OUTF && f32m;
    const int colbase = nb * 128 + wc * 64;
    float bv[4];
#pragma unroll
    for (int ni = 0; ni < 4; ++ni) {
        const int cg = colbase + ni * 16 + l16;
        bv[ni] = f32m ? ((const float*)bias)[cg] : bf2f(((const ushort*)bias)[cg]);
    }
    const int rowb = mb * 128 + wr * 64 + quad * 4;
#pragma unroll
    for (int mi = 0; mi < 4; ++mi) {
#pragma unroll
        for (int r = 0; r < 4; ++r) {
            const int rowg = rowb + mi * 16 + r;   // == b*1024 + pos
            float v[4];
#pragma unroll
            for (int ni = 0; ni < 4; ++ni) v[ni] = acc[mi][ni][r] + bv[ni];
            if constexpr (EPI == 1) {
#pragma unroll
                for (int t = 0; t < 2; ++t) {
                    const size_t ci = (size_t)rowg * 64 + t * 16 + l16;
                    const float c = f32m ? ((const float*)rc)[ci] : bf2f(((const ushort*)rc)[ci]);
                    const float s = f32m ? ((const float*)rs)[ci] : bf2f(((const ushort*)rs)[ci]);
                    const float x1 = v[t], x2 = v[t + 2];
                    v[t]     = x1 * c - x2 * s;
                    v[t + 2] = x2 * c + x1 * s;
                }
            } else if constexpr (EPI == 2) {
#pragma unroll
                for (int t = 0; t < 4; ++t) v[t] = 1.0f / (1.0f + __expf(-v[t]));
            }
#pragma unroll
            for (int ni = 0; ni < 4; ++ni) {
                const size_t idx = (size_t)rowg * Nd + colbase + ni * 16 + l16;
                if (of32) ((float*)C)[idx] = v[ni];
                else      ((ushort*)C)[idx] = f2bf(v[ni]);
            }
        }
    }
}

// ---------------------------------------------------------------------------
// Per-batch transpose: Vp[b*1024 + pos][col] -> Vt[b*1024 + col][pos]
// ---------------------------------------------------------------------------
__global__ __launch_bounds__(256) void transpose_vh(
    const ushort* __restrict__ Vp, ushort* __restrict__ Vt)
{
    const int bb = blockIdx.x >> 8;
    const int pr = (blockIdx.x >> 4) & 15;
    const int cr = blockIdx.x & 15;
    __shared__ ushort t[64 * 65];
    const int tid = threadIdx.x;
    {
        const int r = tid >> 3, c8 = (tid & 7) * 8;
#pragma unroll
        for (int hh = 0; hh < 2; ++hh) {
            const int rr = r + hh * 32;
            const ushort8 v = *(const ushort8*)(Vp + ((size_t)(bb * 1024 + pr * 64 + rr)) * 1024 + cr * 64 + c8);
#pragma unroll
            for (int i = 0; i < 8; ++i) t[rr * 65 + c8 + i] = v[i];
        }
    }
    __syncthreads();
    {
        const int c = tid >> 2, p0 = (tid & 3) * 16;
        ushort8 o0, o1;
#pragma unroll
        for (int i = 0; i < 8; ++i) {
            o0[i] = t[(p0 + i) * 65 + c];
            o1[i] = t[(p0 + 8 + i) * 65 + c];
        }
        ushort* dst = Vt + ((size_t)(bb * 1024 + cr * 64 + c)) * 1024 + pr * 64 + p0;
        *(ushort8*)dst       = o0;
        *(ushort8*)(dst + 8) = o1;
    }
}

// ---------------------------------------------------------------------------
// Flash attention v4: 4 waves/block, each wave owns 32 q-rows (two 16-row
// sub-tiles) -> 128 q-rows/block, 8 blocks per (b,h). KVBLK=64.
// K and V(transposed) tiles staged to LDS via global_load_lds with
// source-side XOR swizzle (linear dest; read applies same XOR -> ~2-way
// bank conflicts instead of 16-way). Double-buffered, 1 barrier/iter.
// Per-(wave,u) private P-bounce. Mask staged to LDS once. Gate fused.
// ---------------------------------------------------------------------------
__global__ __launch_bounds__(256, 3) void attn_kernel(
    const ushort* __restrict__ Qp, const ushort* __restrict__ Kp,
    const ushort* __restrict__ Vt, const ushort* __restrict__ G,
    const unsigned char* __restrict__ mask, ushort* __restrict__ O)
{
    // grid 1024 = 8 qb x 16 h x 8 b; XCD swizzle puts each batch on one XCD.
    const int swz = (blockIdx.x & 7) * 128 + (blockIdx.x >> 3);
    const int qb = swz & 7;
    const int h  = (swz >> 3) & 15;
    const int b  = swz >> 7;
    const int tid  = threadIdx.x;
    const int wave = tid >> 6;
    const int lane = tid & 63;
    const int quad = lane >> 4;
    const int l16  = lane & 15;
    const size_t Dm = 1024;

    __shared__ __align__(16) ushort Ks[2][64 * 64];     // 8KB each: 64 keys x 64 hd
    __shared__ __align__(16) ushort Vs[2][64 * 64];     // 64 hd x 64 pos (from Vt)
    __shared__ __align__(16) ushort Ps[4][2][16 * 72];  // per-(wave,u) P bounce
    __shared__ __align__(4) unsigned char Ms[1024];

    const int q0 = qb * 128 + wave * 32;
    bf16x8 qa[2][2];
#pragma unroll
    for (int u = 0; u < 2; ++u) {
        const ushort* Qb = Qp + ((size_t)b * 1024 + q0 + u * 16 + l16) * Dm + h * 64 + quad * 8;
        qa[u][0] = ld8(Qb);
        qa[u][1] = ld8(Qb + 32);
    }
    const ushort* Kbase = Kp + ((size_t)b * 1024) * Dm + h * 64;      // row stride Dm
    const ushort* Vbase = Vt + ((size_t)b * 1024 + h * 64) * 1024;    // row=hd, stride 1024

    // stage 64x64 bf16 tile; LDS slot t<16B> holds global (row=t>>3, col8=(t&7)^(row&7))
    auto stageK = [&](ushort* lds, int k0) {
#pragma unroll
        for (int j = 0; j < 2; ++j) {
            const int t = j * 256 + tid;
            const int row = t >> 3;
            const int col8 = (t & 7) ^ (row & 7);
            glds16(Kbase + (size_t)(k0 + row) * Dm + col8 * 8, &lds[t * 8]);
        }
    };
    auto stageV = [&](ushort* lds, int k0) {
#pragma unroll
        for (int j = 0; j < 2; ++j) {
            const int t = j * 256 + tid;
            const int row = t >> 3;                    // hd
            const int col8 = (t & 7) ^ (row & 7);      // pos/8 within tile
            glds16(Vbase + (size_t)row * 1024 + k0 + col8 * 8, &lds[t * 8]);
        }
    };

    // prologue: tile 0 + mask
    stageK(Ks[0], 0);
    stageV(Vs[0], 0);
    ((unsigned int*)Ms)[tid] = ((const unsigned int*)(mask + (size_t)b * 1024))[tid];

    float m_r[2][4], l_r[2][4];
    f32x4 o[2][4] = {};
#pragma unroll
    for (int u = 0; u < 2; ++u)
#pragma unroll
        for (int r = 0; r < 4; ++r) { m_r[u][r] = -3.0e38f; l_r[u][r] = 0.0f; }

    const float scale = 0.125f;   // 1/sqrt(64)
    int cur = 0;
    for (int kt = 0; kt < 16; ++kt) {
        __syncthreads();                  // buf[cur] staged; mask ready (kt==0)
        if (kt < 15) {
            stageK(Ks[cur ^ 1], (kt + 1) * 64);
            stageV(Vs[cur ^ 1], (kt + 1) * 64);
        }
        const int k0 = kt * 64;
        // K fragments (shared by both u sub-tiles)
        bf16x8 kf[4][2];
#pragma unroll
        for (int ct = 0; ct < 4; ++ct) {
            const int row = ct * 16 + l16;
#pragma unroll
            for (int kk = 0; kk < 2; ++kk) {
                const int col8 = (kk * 4 + quad) ^ (row & 7);
                kf[ct][kk] = ld8(&Ks[cur][row * 64 + col8 * 8]);
            }
        }
        f32x4 s[2][4] = {};
        __builtin_amdgcn_s_setprio(1);
#pragma unroll
        for (int u = 0; u < 2; ++u)
#pragma unroll
            for (int ct = 0; ct < 4; ++ct) {
                s[u][ct] = __builtin_amdgcn_mfma_f32_16x16x32_bf16(qa[u][0], kf[ct][0], s[u][ct], 0, 0, 0);
                s[u][ct] = __builtin_amdgcn_mfma_f32_16x16x32_bf16(qa[u][1], kf[ct][1], s[u][ct], 0, 0, 0);
            }
        __builtin_amdgcn_s_setprio(0);
        // online softmax per u, per q-row (row = quad*4+r), P bounce per (u,r)
#pragma unroll
        for (int u = 0; u < 2; ++u) {
#pragma unroll
            for (int r = 0; r < 4; ++r) {
                float sv[4];
#pragma unroll
                for (int ct = 0; ct < 4; ++ct)
                    sv[ct] = Ms[k0 + ct * 16 + l16] ? -1e30f : s[u][ct][r] * scale;
                float mx = fmaxf(fmaxf(sv[0], sv[1]), fmaxf(sv[2], sv[3]));
#pragma unroll
                for (int off = 8; off >= 1; off >>= 1) mx = fmaxf(mx, __shfl_xor(mx, off, 16));
                const float mnew  = fmaxf(m_r[u][r], mx);
                const float alpha = __expf(m_r[u][r] - mnew);
                float p[4], ps = 0.0f;
#pragma unroll
                for (int ct = 0; ct < 4; ++ct) { p[ct] = __expf(sv[ct] - mnew); ps += p[ct]; }
#pragma unroll
                for (int off = 8; off >= 1; off >>= 1) ps += __shfl_xor(ps, off, 16);
                l_r[u][r] = l_r[u][r] * alpha + ps;
                m_r[u][r] = mnew;
#pragma unroll
                for (int t = 0; t < 4; ++t) o[u][t][r] *= alpha;
#pragma unroll
                for (int ct = 0; ct < 4; ++ct)
                    Ps[wave][u][(quad * 4 + r) * 72 + ct * 16 + l16] =
                        __builtin_bit_cast(ushort, (__bf16)p[ct]);
            }
        }
        asm volatile("s_waitcnt lgkmcnt(0)" ::: "memory");
        __builtin_amdgcn_sched_barrier(0);
        bf16x8 pa[2][2];
#pragma unroll
        for (int u = 0; u < 2; ++u) {
            pa[u][0] = ld8(&Ps[wave][u][l16 * 72 + quad * 8]);
            pa[u][1] = ld8(&Ps[wave][u][l16 * 72 + 32 + quad * 8]);
        }
        // V fragments (shared by both u)
        bf16x8 vf[4][2];
#pragma unroll
        for (int t = 0; t < 4; ++t) {
            const int row = t * 16 + l16;              // hd
#pragma unroll
            for (int kk = 0; kk < 2; ++kk) {
                const int col8 = (kk * 4 + quad) ^ (row & 7);
                vf[t][kk] = ld8(&Vs[cur][row * 64 + col8 * 8]);
            }
        }
        __builtin_amdgcn_s_setprio(1);
#pragma unroll
        for (int u = 0; u < 2; ++u)
#pragma unroll
            for (int t = 0; t < 4; ++t) {
                o[u][t] = __builtin_amdgcn_mfma_f32_16x16x32_bf16(pa[u][0], vf[t][0], o[u][t], 0, 0, 0);
                o[u][t] = __builtin_amdgcn_mfma_f32_16x16x32_bf16(pa[u][1], vf[t][1], o[u][t], 0, 0, 0);
            }
        __builtin_amdgcn_s_setprio(0);
        cur ^= 1;
    }
    // epilogue: normalize, gate, store bf16
#pragma unroll
    for (int u = 0; u < 2; ++u) {
        const int rowg0 = b * 1024 + q0 + u * 16 + quad * 4;
#pragma unroll
        for (int r = 0; r < 4; ++r) {
            const float inv = 1.0f / l_r[u][r];
#pragma unroll
            for (int t = 0; t < 4; ++t) {
                const size_t idx = (size_t)(rowg0 + r) * Dm + h * 64 + t * 16 + l16;
                O[idx] = f2bf(o[u][t][r] * inv * bf2f(G[idx]));
            }
        }
    }
}

extern "C" void kernel_launch(void* const* d_in, const int* in_sizes, int n_in,
                              void* d_out, int out_size, void* d_ws, size_t ws_size,
                              hipStream_t stream)
{
    const void* query = d_in[0];
    const void* key   = d_in[1];
    const void* value = d_in[2];
    const void* Wq    = d_in[3];
    const void* bq    = d_in[4];
    const void* Wk    = d_in[5];
    const void* bk    = d_in[6];
    const void* Wv    = d_in[7];
    const void* bv    = d_in[8];
    const void* Wg    = d_in[9];
    const void* bg    = d_in[10];
    const void* Wo    = d_in[11];
    const void* bo    = d_in[12];
    const void* rc    = d_in[13];
    const void* rs    = d_in[14];
    const unsigned char* mask = (const unsigned char*)d_in[15];

    char* ws = (char*)d_ws;
    const size_t MB = (size_t)1 << 20;
    const size_t MB16 = 16 * MB;
    const bool big = ws_size >= 139 * MB;

    ushort* Qp = (ushort*)(ws);
    ushort* Kp = (ushort*)(ws + 1 * MB16);
    ushort* Vp = (ushort*)(ws + 2 * MB16);
    ushort* Gt = (ushort*)(ws + 3 * MB16);
    ushort* Vt = (ushort*)(ws + 4 * MB16);
    ushort* Ag = (ushort*)(ws + 2 * MB16);       // alias Vp: dead after transpose
    int*  flag = (int*)(ws + (big ? 138 * MB : 5 * MB16));

    const dim3 gb(512), gt(256);
    hipLaunchKernelGGL(sniff_kernel, dim3(1), dim3(64), 0, stream, (const ushort*)query, flag);

    if (big) {
        ushort* qbf = (ushort*)(ws + 80 * MB);
        ushort* kbf = (ushort*)(ws + 96 * MB);
        ushort* vbf = (ushort*)(ws + 112 * MB);
        ushort* wb[5];
        for (int i = 0; i < 5; ++i) wb[i] = (ushort*)(ws + 128 * MB + (size_t)i * 2 * MB);

        hipLaunchKernelGGL(cvt_kernel, dim3(2048), dim3(256), 0, stream, query, qbf, 1048576, flag);
        hipLaunchKernelGGL(cvt_kernel, dim3(2048), dim3(256), 0, stream, key,   kbf, 1048576, flag);
        hipLaunchKernelGGL(cvt_kernel, dim3(2048), dim3(256), 0, stream, value, vbf, 1048576, flag);
        hipLaunchKernelGGL(cvt_kernel, dim3(512),  dim3(256), 0, stream, Wq, wb[0], 131072, flag);
        hipLaunchKernelGGL(cvt_kernel, dim3(512),  dim3(256), 0, stream, Wk, wb[1], 131072, flag);
        hipLaunchKernelGGL(cvt_kernel, dim3(512),  dim3(256), 0, stream, Wv, wb[2], 131072, flag);
        hipLaunchKernelGGL(cvt_kernel, dim3(512),  dim3(256), 0, stream, Wg, wb[3], 131072, flag);
        hipLaunchKernelGGL(cvt_kernel, dim3(512),  dim3(256), 0, stream, Wo, wb[4], 131072, flag);

        hipLaunchKernelGGL((gemm_bt<1,1,1,0>), gb, gt, 0, stream, qbf, wb[0], bq, rc, rs, Qp, flag);
        hipLaunchKernelGGL((gemm_bt<1,1,1,0>), gb, gt, 0, stream, kbf, wb[1], bk, rc, rs, Kp, flag);
        hipLaunchKernelGGL((gemm_bt<0,1,1,0>), gb, gt, 0, stream, vbf, wb[2], bv, rc, rs, Vp, flag);
        hipLaunchKernelGGL((gemm_bt<2,1,1,0>), gb, gt, 0, stream, qbf, wb[3], bg, rc, rs, Gt, flag);

        hipLaunchKernelGGL(transpose_vh, dim3(2048), dim3(256), 0, stream, Vp, Vt);
        hipLaunchKernelGGL(attn_kernel,  dim3(1024), dim3(256), 0, stream, Qp, Kp, Vt, Gt, mask, Ag);

        hipLaunchKernelGGL((gemm_bt<0,1,1,1>), gb, gt, 0, stream, Ag, wb[4], bo, rc, rs, d_out, flag);
    } else {
        hipLaunchKernelGGL((gemm_bt<1,0,0,0>), gb, gt, 0, stream, query, Wq, bq, rc, rs, Qp, flag);
        hipLaunchKernelGGL((gemm_bt<1,0,0,0>), gb, gt, 0, stream, key,   Wk, bk, rc, rs, Kp, flag);
        hipLaunchKernelGGL((gemm_bt<0,0,0,0>), gb, gt, 0, stream, value, Wv, bv, rc, rs, Vp, flag);
        hipLaunchKernelGGL((gemm_bt<2,0,0,0>), gb, gt, 0, stream, query, Wg, bg, rc, rs, Gt, flag);

        hipLaunchKernelGGL(transpose_vh, dim3(2048), dim3(256), 0, stream, Vp, Vt);
        hipLaunchKernelGGL(attn_kernel,  dim3(1024), dim3(256), 0, stream, Qp, Kp, Vt, Gt, mask, Ag);

        hipLaunchKernelGGL((gemm_bt<0,1,0,1>), gb, gt, 0, stream, Ag, Wo, bo, rc, rs, d_out, flag);
    }
}

// Round 6
// 411.377 us; speedup vs baseline: 1.6000x; 1.1255x over previous
//
#include <hip/hip_runtime.h>

using ushort  = unsigned short;
using bf16x8  = __attribute__((ext_vector_type(8))) __bf16;
using bf16x4  = __attribute__((ext_vector_type(4))) __bf16;
using ushort8 = __attribute__((ext_vector_type(8))) unsigned short;
using f32x4   = __attribute__((ext_vector_type(4))) float;
using float4v = __attribute__((ext_vector_type(4))) float;

__device__ __forceinline__ float bf2f(ushort u) {
    union { unsigned int i; float f; } v; v.i = ((unsigned int)u) << 16; return v.f;
}
__device__ __forceinline__ ushort f2bf(float f) {
    union { float f; unsigned int i; } v; v.f = f;
    unsigned int r = v.i + 0x7FFFu + ((v.i >> 16) & 1u);
    return (ushort)(r >> 16);
}
__device__ __forceinline__ bf16x8 ld8(const ushort* p) {
    return __builtin_bit_cast(bf16x8, *(const ushort8*)p);
}
// async global->LDS, 16B per lane (dest = wave-uniform base + lane*16)
__device__ __forceinline__ void glds16(const void* g, void* l) {
    __builtin_amdgcn_global_load_lds(
        (const __attribute__((address_space(1))) unsigned int*)g,
        (__attribute__((address_space(3))) unsigned int*)l, 16, 0, 0);
}

// ---------------------------------------------------------------------------
// Dtype sniffer: bf16 (flag=0) vs f32 (flag=1) storage, decided from `query`.
// ---------------------------------------------------------------------------
__global__ void sniff_kernel(const ushort* __restrict__ q, int* __restrict__ flag) {
    const int lane = threadIdx.x;              // 64 threads, 1 block
    float mx = 0.0f;
    for (int i = lane; i < 512; i += 64) {
        float v = bf2f(q[2 * i]);              // even halfword
        mx = fmaxf(mx, fabsf(v));
    }
#pragma unroll
    for (int off = 32; off >= 1; off >>= 1) mx = fmaxf(mx, __shfl_xor(mx, off, 64));
    if (lane == 0) *flag = (mx > 1.0e6f) ? 1 : 0;
}

// ---------------------------------------------------------------------------
// Convert-or-copy 8 elements at vec8 index i.
// ---------------------------------------------------------------------------
__device__ __forceinline__ void cvt8(const void* src, ushort* dst, int i, bool f32m) {
    if (f32m) {
        const float4v a = ((const float4v*)src)[2 * i];
        const float4v b = ((const float4v*)src)[2 * i + 1];
        bf16x8 o;
#pragma unroll
        for (int j = 0; j < 4; ++j) { o[j] = (__bf16)a[j]; o[j + 4] = (__bf16)b[j]; }
        ((ushort8*)dst)[i] = __builtin_bit_cast(ushort8, o);
    } else {
        ((ushort8*)dst)[i] = ((const ushort8*)src)[i];
    }
}

// q/k/v activations: 3 segments x 1M vec8, grid 3*2048
__global__ __launch_bounds__(256) void cvt_qkv(
    const void* __restrict__ s0, const void* __restrict__ s1, const void* __restrict__ s2,
    ushort* __restrict__ d0, ushort* __restrict__ d1, ushort* __restrict__ d2,
    const int* __restrict__ flag)
{
    const bool f32m = (*flag != 0);
    const int seg = blockIdx.x >> 11;
    const void* src = seg == 0 ? s0 : (seg == 1 ? s1 : s2);
    ushort*    dst = seg == 0 ? d0 : (seg == 1 ? d1 : d2);
    for (int i = (blockIdx.x & 2047) * 256 + threadIdx.x; i < 1048576; i += 2048 * 256)
        cvt8(src, dst, i, f32m);
}
// 5 weight matrices: 5 segments x 128K vec8, grid 5*512
__global__ __launch_bounds__(256) void cvt_w5(
    const void* __restrict__ s0, const void* __restrict__ s1, const void* __restrict__ s2,
    const void* __restrict__ s3, const void* __restrict__ s4,
    ushort* __restrict__ d0, ushort* __restrict__ d1, ushort* __restrict__ d2,
    ushort* __restrict__ d3, ushort* __restrict__ d4,
    const int* __restrict__ flag)
{
    const bool f32m = (*flag != 0);
    const int seg = blockIdx.x >> 9;
    const void* src = seg == 0 ? s0 : seg == 1 ? s1 : seg == 2 ? s2 : seg == 3 ? s3 : s4;
    ushort*    dst = seg == 0 ? d0 : seg == 1 ? d1 : seg == 2 ? d2 : seg == 3 ? d3 : d4;
    cvt8(src, dst, (blockIdx.x & 511) * 256 + threadIdx.x, f32m);
}

// ---------------------------------------------------------------------------
// C[M=8192, N=1024] = A[M,K=1024] * W[N,K]^T + bias.
// 128x128 tile, BK=32, 4 waves, double-buffered LDS, XCD swizzle.
// EPI 0: none  1: RoPE  2: sigmoid  3: RoPE * 0.125 (pre-scaled Q)
// ---------------------------------------------------------------------------
template<int EPI, int ABF16, int WBF16, int OUTF>
__global__ __launch_bounds__(256) void gemm_bt(
    const void* __restrict__ A, const void* __restrict__ W,
    const void* __restrict__ bias,
    const void* __restrict__ rc, const void* __restrict__ rs,
    void* __restrict__ C, const int* __restrict__ flag)
{
    constexpr int Kd = 1024, Nd = 1024;
    const bool f32m = (*flag != 0);
    const bool af32 = f32m && !ABF16;
    const bool wf32 = f32m && !WBF16;

    const int tid  = threadIdx.x;
    const int swz  = (blockIdx.x & 7) * 64 + (blockIdx.x >> 3);
    const int nb   = swz & 7;           // N/128 = 8
    const int mb   = swz >> 3;          // M/128 = 64
    const int wave = tid >> 6;
    const int lane = tid & 63;
    const int quad = lane >> 4;
    const int l16  = lane & 15;
    const int wr   = wave >> 1;
    const int wc   = wave & 1;

    __shared__ __align__(16) ushort As[2][128 * 32];
    __shared__ __align__(16) ushort Bs[2][128 * 32];

    const int arow0 = mb * 128;
    const int brow0 = nb * 128;

    auto ldregs = [&](float4v r[4], const float* src, int row0, int k0) {
#pragma unroll
        for (int j = 0; j < 2; ++j) {
            const int c = j * 256 + tid;
            const float* gp = src + (size_t)(row0 + (c >> 2)) * Kd + k0 + (c & 3) * 8;
            r[2 * j]     = *(const float4v*)gp;
            r[2 * j + 1] = *(const float4v*)(gp + 4);
        }
    };
    auto cvtwr = [&](ushort* lds, const float4v r[4]) {
#pragma unroll
        for (int j = 0; j < 2; ++j) {
            const int c = j * 256 + tid;
            bf16x8 o;
#pragma unroll
            for (int i = 0; i < 4; ++i) {
                o[i]     = (__bf16)r[2 * j][i];
                o[i + 4] = (__bf16)r[2 * j + 1][i];
            }
            *(ushort8*)&lds[c * 8] = __builtin_bit_cast(ushort8, o);
        }
    };
    auto stage16 = [&](ushort* lds, const ushort* src, int row0, int k0) {
#pragma unroll
        for (int j = 0; j < 2; ++j) {
            const int c = j * 256 + tid;
            glds16(src + (size_t)(row0 + (c >> 2)) * Kd + k0 + (c & 3) * 8, &lds[c * 8]);
        }
    };

    {
        float4v t[4];
        if (af32) { ldregs(t, (const float*)A, arow0, 0); cvtwr(As[0], t); }
        else      stage16(As[0], (const ushort*)A, arow0, 0);
        if (wf32) { ldregs(t, (const float*)W, brow0, 0); cvtwr(Bs[0], t); }
        else      stage16(Bs[0], (const ushort*)W, brow0, 0);
    }

    f32x4 acc[4][4] = {};
    int cur = 0;
    for (int kt = 0; kt < 32; ++kt) {
        __syncthreads();
        const bool pf = (kt < 31);
        const int  kn = (kt + 1) * 32;
        float4v ra[4], rb[4];
        if (pf) {
            if (af32) ldregs(ra, (const float*)A, arow0, kn);
            else      stage16(As[cur ^ 1], (const ushort*)A, arow0, kn);
            if (wf32) ldregs(rb, (const float*)W, brow0, kn);
            else      stage16(Bs[cur ^ 1], (const ushort*)W, brow0, kn);
        }
        bf16x8 fa[4], fb[4];
#pragma unroll
        for (int mi = 0; mi < 4; ++mi)
            fa[mi] = ld8(&As[cur][(wr * 64 + mi * 16 + l16) * 32 + quad * 8]);
#pragma unroll
        for (int ni = 0; ni < 4; ++ni)
            fb[ni] = ld8(&Bs[cur][(wc * 64 + ni * 16 + l16) * 32 + quad * 8]);
#pragma unroll
        for (int mi = 0; mi < 4; ++mi)
#pragma unroll
            for (int ni = 0; ni < 4; ++ni)
                acc[mi][ni] = __builtin_amdgcn_mfma_f32_16x16x32_bf16(fa[mi], fb[ni], acc[mi][ni], 0, 0, 0);
        if (pf) {
            if (af32) cvtwr(As[cur ^ 1], ra);
            if (wf32) cvtwr(Bs[cur ^ 1], rb);
        }
        cur ^= 1;
    }

    const bool of32 = OUTF && f32m;
    const int colbase = nb * 128 + wc * 64;
    float bv[4];
#pragma unroll
    for (int ni = 0; ni < 4; ++ni) {
        const int cg = colbase + ni * 16 + l16;
        bv[ni] = f32m ? ((const float*)bias)[cg] : bf2f(((const ushort*)bias)[cg]);
    }
    const int rowb = mb * 128 + wr * 64 + quad * 4;
#pragma unroll
    for (int mi = 0; mi < 4; ++mi) {
#pragma unroll
        for (int r = 0; r < 4; ++r) {
            const int rowg = rowb + mi * 16 + r;   // == b*1024 + pos
            float v[4];
#pragma unroll
            for (int ni = 0; ni < 4; ++ni) v[ni] = acc[mi][ni][r] + bv[ni];
            if constexpr (EPI == 1 || EPI == 3) {
#pragma unroll
                for (int t = 0; t < 2; ++t) {
                    const size_t ci = (size_t)rowg * 64 + t * 16 + l16;
                    const float c = f32m ? ((const float*)rc)[ci] : bf2f(((const ushort*)rc)[ci]);
                    const float s = f32m ? ((const float*)rs)[ci] : bf2f(((const ushort*)rs)[ci]);
                    const float x1 = v[t], x2 = v[t + 2];
                    v[t]     = x1 * c - x2 * s;
                    v[t + 2] = x2 * c + x1 * s;
                }
                if constexpr (EPI == 3) {
#pragma unroll
                    for (int t = 0; t < 4; ++t) v[t] *= 0.125f;   // fold 1/sqrt(hd)
                }
            } else if constexpr (EPI == 2) {
#pragma unroll
                for (int t = 0; t < 4; ++t) v[t] = 1.0f / (1.0f + __expf(-v[t]));
            }
#pragma unroll
            for (int ni = 0; ni < 4; ++ni) {
                const size_t idx = (size_t)rowg * Nd + colbase + ni * 16 + l16;
                if (of32) ((float*)C)[idx] = v[ni];
                else      ((ushort*)C)[idx] = f2bf(v[ni]);
            }
        }
    }
}

// ---------------------------------------------------------------------------
// Per-batch transpose: Vp[b*1024 + pos][col] -> Vt[b*1024 + col][pos]
// ---------------------------------------------------------------------------
__global__ __launch_bounds__(256) void transpose_vh(
    const ushort* __restrict__ Vp, ushort* __restrict__ Vt)
{
    const int bb = blockIdx.x >> 8;
    const int pr = (blockIdx.x >> 4) & 15;
    const int cr = blockIdx.x & 15;
    __shared__ ushort t[64 * 65];
    const int tid = threadIdx.x;
    {
        const int r = tid >> 3, c8 = (tid & 7) * 8;
#pragma unroll
        for (int hh = 0; hh < 2; ++hh) {
            const int rr = r + hh * 32;
            const ushort8 v = *(const ushort8*)(Vp + ((size_t)(bb * 1024 + pr * 64 + rr)) * 1024 + cr * 64 + c8);
#pragma unroll
            for (int i = 0; i < 8; ++i) t[rr * 65 + c8 + i] = v[i];
        }
    }
    __syncthreads();
    {
        const int c = tid >> 2, p0 = (tid & 3) * 16;
        ushort8 o0, o1;
#pragma unroll
        for (int i = 0; i < 8; ++i) {
            o0[i] = t[(p0 + i) * 65 + c];
            o1[i] = t[(p0 + 8 + i) * 65 + c];
        }
        ushort* dst = Vt + ((size_t)(bb * 1024 + cr * 64 + c)) * 1024 + pr * 64 + p0;
        *(ushort8*)dst       = o0;
        *(ushort8*)(dst + 8) = o1;
    }
}

// ---------------------------------------------------------------------------
// Flash attention v5: 8 waves/block x 32 q-rows (2 u-tiles) = 256 rows/block.
// Swapped QK^T (mfma(K,Q)) -> per-lane holds 16 keys of ONE q-row:
//   max-reduce = in-lane + 2 shuffles; l kept as lane-local partial (reduced
//   once in epilogue); P packed to ds_write_b64. Defer-max (THR=8) makes the
//   O-rescale + alpha redistribution rare. Scale pre-folded into Q.
// K/V staged via glds16 + source-XOR swizzle, double-buffered, 1 barrier/iter.
// Mask: one-time any() check; per-key masking only on the rare masked path.
// ---------------------------------------------------------------------------
__global__ __launch_bounds__(512) void attn_kernel(
    const ushort* __restrict__ Qp, const ushort* __restrict__ Kp,
    const ushort* __restrict__ Vt, const ushort* __restrict__ G,
    const unsigned char* __restrict__ mask, ushort* __restrict__ O)
{
    // grid 512 = 8 XCD x 64; each XCD owns one batch (K/V L2-resident).
    const int swz = (blockIdx.x & 7) * 64 + (blockIdx.x >> 3);
    const int qb = swz & 3;                  // 256-row q-block
    const int h  = (swz >> 2) & 15;
    const int b  = swz >> 6;
    const int tid  = threadIdx.x;
    const int wave = tid >> 6;
    const int lane = tid & 63;
    const int quad = lane >> 4;
    const int l16  = lane & 15;
    const size_t Dm = 1024;

    __shared__ __align__(16) ushort Ks[2][64 * 64];
    __shared__ __align__(16) ushort Vs[2][64 * 64];
    __shared__ __align__(16) ushort Ps[8][16 * 72];
    __shared__ __align__(16) unsigned char Ms[1024];

    const int q0 = qb * 256 + wave * 32;
    bf16x8 qa[2][2];
#pragma unroll
    for (int u = 0; u < 2; ++u) {
        const ushort* Qb = Qp + ((size_t)b * 1024 + q0 + u * 16 + l16) * Dm + h * 64 + quad * 8;
        qa[u][0] = ld8(Qb);
        qa[u][1] = ld8(Qb + 32);
    }
    const ushort* Kbase = Kp + ((size_t)b * 1024) * Dm + h * 64;
    const ushort* Vbase = Vt + ((size_t)b * 1024 + h * 64) * 1024;

    // stage 64x64 tile: slot t holds global (row=t>>3, col8=(t&7)^(row&7))
    auto stageK = [&](ushort* lds, int k0) {
        const int row = tid >> 3;
        const int col8 = (tid & 7) ^ (row & 7);
        glds16(Kbase + (size_t)(k0 + row) * Dm + col8 * 8, &lds[tid * 8]);
    };
    auto stageV = [&](ushort* lds, int k0) {
        const int row = tid >> 3;
        const int col8 = (tid & 7) ^ (row & 7);
        glds16(Vbase + (size_t)row * 1024 + k0 + col8 * 8, &lds[tid * 8]);
    };

    stageK(Ks[0], 0);
    stageV(Vs[0], 0);
    if (tid < 256)
        ((unsigned int*)Ms)[tid] = ((const unsigned int*)(mask + (size_t)b * 1024))[tid];
    __syncthreads();
    bool anym;
    {
        const unsigned long long* M8 = (const unsigned long long*)Ms;
        anym = __any((M8[lane] | M8[lane + 64]) != 0ULL);
    }

    float m_r[2] = { -3.0e38f, -3.0e38f };
    float l_r[2] = { 0.0f, 0.0f };
    f32x4 o[2][4] = {};

    int cur = 0;
    for (int kt = 0; kt < 16; ++kt) {
        __syncthreads();                 // buf[cur] staged; buf[cur^1] free
        if (kt < 15) {
            stageK(Ks[cur ^ 1], (kt + 1) * 64);
            stageV(Vs[cur ^ 1], (kt + 1) * 64);
        }
        const int k0 = kt * 64;
        // --- K fragments + swapped QK^T: S^T, row(quad*4+r)=key, col(l16)=q
        bf16x8 kf0[4], kf1[4];
#pragma unroll
        for (int ct = 0; ct < 4; ++ct) {
            const int row = ct * 16 + l16;
            kf0[ct] = ld8(&Ks[cur][row * 64 + ((quad)     ^ (row & 7)) * 8]);
            kf1[ct] = ld8(&Ks[cur][row * 64 + ((4 + quad) ^ (row & 7)) * 8]);
        }
        f32x4 s[2][4] = {};
        __builtin_amdgcn_s_setprio(1);
#pragma unroll
        for (int u = 0; u < 2; ++u)
#pragma unroll
            for (int ct = 0; ct < 4; ++ct) {
                s[u][ct] = __builtin_amdgcn_mfma_f32_16x16x32_bf16(kf0[ct], qa[u][0], s[u][ct], 0, 0, 0);
                s[u][ct] = __builtin_amdgcn_mfma_f32_16x16x32_bf16(kf1[ct], qa[u][1], s[u][ct], 0, 0, 0);
            }
        __builtin_amdgcn_s_setprio(0);
        // --- V fragments (shared by both u)
        bf16x8 vf[4][2];
#pragma unroll
        for (int t = 0; t < 4; ++t) {
            const int row = t * 16 + l16;
#pragma unroll
            for (int kk = 0; kk < 2; ++kk)
                vf[t][kk] = ld8(&Vs[cur][row * 64 + (((kk * 4 + quad) ^ (row & 7))) * 8]);
        }
        // --- per u: softmax (lane-local row), P write, PV
#pragma unroll
        for (int u = 0; u < 2; ++u) {
            float sv[4][4];
#pragma unroll
            for (int ct = 0; ct < 4; ++ct)
#pragma unroll
                for (int r = 0; r < 4; ++r) sv[ct][r] = s[u][ct][r];
            if (anym) {
#pragma unroll
                for (int ct = 0; ct < 4; ++ct) {
                    const unsigned int mb4 = *(const unsigned int*)&Ms[k0 + ct * 16 + quad * 4];
#pragma unroll
                    for (int r = 0; r < 4; ++r)
                        if ((mb4 >> (8 * r)) & 0xffu) sv[ct][r] = -1e30f;
                }
            }
            float mxv = sv[0][0];
#pragma unroll
            for (int ct = 0; ct < 4; ++ct)
#pragma unroll
                for (int r = 0; r < 4; ++r) mxv = fmaxf(mxv, sv[ct][r]);
            mxv = fmaxf(mxv, __shfl_xor(mxv, 16, 64));
            mxv = fmaxf(mxv, __shfl_xor(mxv, 32, 64));
            if (__any(mxv > m_r[u] + 8.0f)) {          // rare: real max growth
                const float mnew  = fmaxf(m_r[u], mxv);
                const float alpha = __expf(m_r[u] - mnew);
                l_r[u] *= alpha;
                m_r[u]  = mnew;
#pragma unroll
                for (int r = 0; r < 4; ++r) {
                    const float ar = __shfl(alpha, quad * 4 + r, 64);
#pragma unroll
                    for (int t = 0; t < 4; ++t) o[u][t][r] *= ar;
                }
            }
            float ls = 0.0f;
            bf16x4 w[4];
#pragma unroll
            for (int ct = 0; ct < 4; ++ct)
#pragma unroll
                for (int r = 0; r < 4; ++r) {
                    const float pv = __expf(sv[ct][r] - m_r[u]);   // bounded by e^8
                    ls += pv;
                    w[ct][r] = (__bf16)pv;
                }
            l_r[u] += ls;
#pragma unroll
            for (int ct = 0; ct < 4; ++ct)
                *(bf16x4*)&Ps[wave][l16 * 72 + ct * 16 + quad * 4] = w[ct];
            asm volatile("s_waitcnt lgkmcnt(0)" ::: "memory");
            __builtin_amdgcn_sched_barrier(0);
            const bf16x8 pa0 = ld8(&Ps[wave][l16 * 72 + quad * 8]);
            const bf16x8 pa1 = ld8(&Ps[wave][l16 * 72 + 32 + quad * 8]);
            __builtin_amdgcn_s_setprio(1);
#pragma unroll
            for (int t = 0; t < 4; ++t) {
                o[u][t] = __builtin_amdgcn_mfma_f32_16x16x32_bf16(pa0, vf[t][0], o[u][t], 0, 0, 0);
                o[u][t] = __builtin_amdgcn_mfma_f32_16x16x32_bf16(pa1, vf[t][1], o[u][t], 0, 0, 0);
            }
            __builtin_amdgcn_s_setprio(0);
        }
        cur ^= 1;
    }
    // epilogue: reduce l across quads once, redistribute, normalize, gate, store
#pragma unroll
    for (int u = 0; u < 2; ++u) {
        float lt = l_r[u];
        lt += __shfl_xor(lt, 16, 64);
        lt += __shfl_xor(lt, 32, 64);
        const int rowg0 = b * 1024 + q0 + u * 16 + quad * 4;
#pragma unroll
        for (int r = 0; r < 4; ++r) {
            const float inv = 1.0f / __shfl(lt, quad * 4 + r, 64);
#pragma unroll
            for (int t = 0; t < 4; ++t) {
                const size_t idx = (size_t)(rowg0 + r) * Dm + h * 64 + t * 16 + l16;
                O[idx] = f2bf(o[u][t][r] * inv * bf2f(G[idx]));
            }
        }
    }
}

extern "C" void kernel_launch(void* const* d_in, const int* in_sizes, int n_in,
                              void* d_out, int out_size, void* d_ws, size_t ws_size,
                              hipStream_t stream)
{
    const void* query = d_in[0];
    const void* key   = d_in[1];
    const void* value = d_in[2];
    const void* Wq    = d_in[3];
    const void* bq    = d_in[4];
    const void* Wk    = d_in[5];
    const void* bk    = d_in[6];
    const void* Wv    = d_in[7];
    const void* bv    = d_in[8];
    const void* Wg    = d_in[9];
    const void* bg    = d_in[10];
    const void* Wo    = d_in[11];
    const void* bo    = d_in[12];
    const void* rc    = d_in[13];
    const void* rs    = d_in[14];
    const unsigned char* mask = (const unsigned char*)d_in[15];

    char* ws = (char*)d_ws;
    const size_t MB = (size_t)1 << 20;
    const size_t MB16 = 16 * MB;
    const bool big = ws_size >= 139 * MB;

    ushort* Qp = (ushort*)(ws);
    ushort* Kp = (ushort*)(ws + 1 * MB16);
    ushort* Vp = (ushort*)(ws + 2 * MB16);
    ushort* Gt = (ushort*)(ws + 3 * MB16);
    ushort* Vt = (ushort*)(ws + 4 * MB16);
    ushort* Ag = (ushort*)(ws + 2 * MB16);       // alias Vp: dead after transpose
    int*  flag = (int*)(ws + (big ? 138 * MB : 5 * MB16));

    const dim3 gb(512), gt(256);
    hipLaunchKernelGGL(sniff_kernel, dim3(1), dim3(64), 0, stream, (const ushort*)query, flag);

    if (big) {
        ushort* qbf = (ushort*)(ws + 80 * MB);
        ushort* kbf = (ushort*)(ws + 96 * MB);
        ushort* vbf = (ushort*)(ws + 112 * MB);
        ushort* wb[5];
        for (int i = 0; i < 5; ++i) wb[i] = (ushort*)(ws + 128 * MB + (size_t)i * 2 * MB);

        hipLaunchKernelGGL(cvt_qkv, dim3(3 * 2048), dim3(256), 0, stream,
                           query, key, value, qbf, kbf, vbf, flag);
        hipLaunchKernelGGL(cvt_w5, dim3(5 * 512), dim3(256), 0, stream,
                           Wq, Wk, Wv, Wg, Wo, wb[0], wb[1], wb[2], wb[3], wb[4], flag);

        hipLaunchKernelGGL((gemm_bt<3,1,1,0>), gb, gt, 0, stream, qbf, wb[0], bq, rc, rs, Qp, flag);
        hipLaunchKernelGGL((gemm_bt<1,1,1,0>), gb, gt, 0, stream, kbf, wb[1], bk, rc, rs, Kp, flag);
        hipLaunchKernelGGL((gemm_bt<0,1,1,0>), gb, gt, 0, stream, vbf, wb[2], bv, rc, rs, Vp, flag);
        hipLaunchKernelGGL((gemm_bt<2,1,1,0>), gb, gt, 0, stream, qbf, wb[3], bg, rc, rs, Gt, flag);

        hipLaunchKernelGGL(transpose_vh, dim3(2048), dim3(256), 0, stream, Vp, Vt);
        hipLaunchKernelGGL(attn_kernel,  dim3(512), dim3(512), 0, stream, Qp, Kp, Vt, Gt, mask, Ag);

        hipLaunchKernelGGL((gemm_bt<0,1,1,1>), gb, gt, 0, stream, Ag, wb[4], bo, rc, rs, d_out, flag);
    } else {
        hipLaunchKernelGGL((gemm_bt<3,0,0,0>), gb, gt, 0, stream, query, Wq, bq, rc, rs, Qp, flag);
        hipLaunchKernelGGL((gemm_bt<1,0,0,0>), gb, gt, 0, stream, key,   Wk, bk, rc, rs, Kp, flag);
        hipLaunchKernelGGL((gemm_bt<0,0,0,0>), gb, gt, 0, stream, value, Wv, bv, rc, rs, Vp, flag);
        hipLaunchKernelGGL((gemm_bt<2,0,0,0>), gb, gt, 0, stream, query, Wg, bg, rc, rs, Gt, flag);

        hipLaunchKernelGGL(transpose_vh, dim3(2048), dim3(256), 0, stream, Vp, Vt);
        hipLaunchKernelGGL(attn_kernel,  dim3(512), dim3(512), 0, stream, Qp, Kp, Vt, Gt, mask, Ag);

        hipLaunchKernelGGL((gemm_bt<0,1,0,1>), gb, gt, 0, stream, Ag, Wo, bo, rc, rs, d_out, flag);
    }
}

// Round 8
// 395.370 us; speedup vs baseline: 1.6648x; 1.0405x over previous
//
#include <hip/hip_runtime.h>

using ushort  = unsigned short;
using bf16x8  = __attribute__((ext_vector_type(8))) __bf16;
using bf16x4  = __attribute__((ext_vector_type(4))) __bf16;
using ushort8 = __attribute__((ext_vector_type(8))) unsigned short;
using f32x4   = __attribute__((ext_vector_type(4))) float;
using float4v = __attribute__((ext_vector_type(4))) float;

__device__ __forceinline__ float bf2f(ushort u) {
    union { unsigned int i; float f; } v; v.i = ((unsigned int)u) << 16; return v.f;
}
__device__ __forceinline__ ushort f2bf(float f) {
    union { float f; unsigned int i; } v; v.f = f;
    unsigned int r = v.i + 0x7FFFu + ((v.i >> 16) & 1u);
    return (ushort)(r >> 16);
}
__device__ __forceinline__ bf16x8 ld8(const ushort* p) {
    return __builtin_bit_cast(bf16x8, *(const ushort8*)p);
}
// async global->LDS, 16B per lane (dest = wave-uniform base + lane*16)
__device__ __forceinline__ void glds16(const void* g, void* l) {
    __builtin_amdgcn_global_load_lds(
        (const __attribute__((address_space(1))) unsigned int*)g,
        (__attribute__((address_space(3))) unsigned int*)l, 16, 0, 0);
}

// ---------------------------------------------------------------------------
// Dtype sniffer: bf16 (flag=0) vs f32 (flag=1) storage, decided from `query`.
// ---------------------------------------------------------------------------
__global__ void sniff_kernel(const ushort* __restrict__ q, int* __restrict__ flag) {
    const int lane = threadIdx.x;              // 64 threads, 1 block
    float mx = 0.0f;
    for (int i = lane; i < 512; i += 64) {
        float v = bf2f(q[2 * i]);              // even halfword
        mx = fmaxf(mx, fabsf(v));
    }
#pragma unroll
    for (int off = 32; off >= 1; off >>= 1) mx = fmaxf(mx, __shfl_xor(mx, off, 64));
    if (lane == 0) *flag = (mx > 1.0e6f) ? 1 : 0;
}

// ---------------------------------------------------------------------------
// Convert-or-copy 8 elements at vec8 index i.
// ---------------------------------------------------------------------------
__device__ __forceinline__ void cvt8(const void* src, ushort* dst, int i, bool f32m) {
    if (f32m) {
        const float4v a = ((const float4v*)src)[2 * i];
        const float4v b = ((const float4v*)src)[2 * i + 1];
        bf16x8 o;
#pragma unroll
        for (int j = 0; j < 4; ++j) { o[j] = (__bf16)a[j]; o[j + 4] = (__bf16)b[j]; }
        ((ushort8*)dst)[i] = __builtin_bit_cast(ushort8, o);
    } else {
        ((ushort8*)dst)[i] = ((const ushort8*)src)[i];
    }
}

// q/k/v activations: 3 segments x 1M vec8, grid 3*2048
__global__ __launch_bounds__(256) void cvt_qkv(
    const void* __restrict__ s0, const void* __restrict__ s1, const void* __restrict__ s2,
    ushort* __restrict__ d0, ushort* __restrict__ d1, ushort* __restrict__ d2,
    const int* __restrict__ flag)
{
    const bool f32m = (*flag != 0);
    const int seg = blockIdx.x >> 11;
    const void* src = seg == 0 ? s0 : (seg == 1 ? s1 : s2);
    ushort*    dst = seg == 0 ? d0 : (seg == 1 ? d1 : d2);
    for (int i = (blockIdx.x & 2047) * 256 + threadIdx.x; i < 1048576; i += 2048 * 256)
        cvt8(src, dst, i, f32m);
}
// 5 weight matrices: 5 segments x 128K vec8, grid 5*512
__global__ __launch_bounds__(256) void cvt_w5(
    const void* __restrict__ s0, const void* __restrict__ s1, const void* __restrict__ s2,
    const void* __restrict__ s3, const void* __restrict__ s4,
    ushort* __restrict__ d0, ushort* __restrict__ d1, ushort* __restrict__ d2,
    ushort* __restrict__ d3, ushort* __restrict__ d4,
    const int* __restrict__ flag)
{
    const bool f32m = (*flag != 0);
    const int seg = blockIdx.x >> 9;
    const void* src = seg == 0 ? s0 : seg == 1 ? s1 : seg == 2 ? s2 : seg == 3 ? s3 : s4;
    ushort*    dst = seg == 0 ? d0 : seg == 1 ? d1 : seg == 2 ? d2 : seg == 3 ? d3 : d4;
    cvt8(src, dst, (blockIdx.x & 511) * 256 + threadIdx.x, f32m);
}

// ---------------------------------------------------------------------------
// Generic GEMM (small-ws fallback and final projection):
// C[M=8192, N=1024] = A * W^T + bias. 128x128 tile, BK=32, 4 waves, dbuf LDS.
// EPI 0: none  1: RoPE  2: sigmoid  3: RoPE * 0.125
// ---------------------------------------------------------------------------
template<int EPI, int ABF16, int WBF16, int OUTF>
__global__ __launch_bounds__(256) void gemm_bt(
    const void* __restrict__ A, const void* __restrict__ W,
    const void* __restrict__ bias,
    const void* __restrict__ rc, const void* __restrict__ rs,
    void* __restrict__ C, const int* __restrict__ flag)
{
    constexpr int Kd = 1024, Nd = 1024;
    const bool f32m = (*flag != 0);
    const bool af32 = f32m && !ABF16;
    const bool wf32 = f32m && !WBF16;

    const int tid  = threadIdx.x;
    const int swz  = (blockIdx.x & 7) * 64 + (blockIdx.x >> 3);
    const int nb   = swz & 7;
    const int mb   = swz >> 3;
    const int wave = tid >> 6;
    const int lane = tid & 63;
    const int quad = lane >> 4;
    const int l16  = lane & 15;
    const int wr   = wave >> 1;
    const int wc   = wave & 1;

    __shared__ __align__(16) ushort As[2][128 * 32];
    __shared__ __align__(16) ushort Bs[2][128 * 32];

    const int arow0 = mb * 128;
    const int brow0 = nb * 128;

    auto ldregs = [&](float4v r[4], const float* src, int row0, int k0) {
#pragma unroll
        for (int j = 0; j < 2; ++j) {
            const int c = j * 256 + tid;
            const float* gp = src + (size_t)(row0 + (c >> 2)) * Kd + k0 + (c & 3) * 8;
            r[2 * j]     = *(const float4v*)gp;
            r[2 * j + 1] = *(const float4v*)(gp + 4);
        }
    };
    auto cvtwr = [&](ushort* lds, const float4v r[4]) {
#pragma unroll
        for (int j = 0; j < 2; ++j) {
            const int c = j * 256 + tid;
            bf16x8 o;
#pragma unroll
            for (int i = 0; i < 4; ++i) {
                o[i]     = (__bf16)r[2 * j][i];
                o[i + 4] = (__bf16)r[2 * j + 1][i];
            }
            *(ushort8*)&lds[c * 8] = __builtin_bit_cast(ushort8, o);
        }
    };
    auto stage16 = [&](ushort* lds, const ushort* src, int row0, int k0) {
#pragma unroll
        for (int j = 0; j < 2; ++j) {
            const int c = j * 256 + tid;
            glds16(src + (size_t)(row0 + (c >> 2)) * Kd + k0 + (c & 3) * 8, &lds[c * 8]);
        }
    };

    {
        float4v t[4];
        if (af32) { ldregs(t, (const float*)A, arow0, 0); cvtwr(As[0], t); }
        else      stage16(As[0], (const ushort*)A, arow0, 0);
        if (wf32) { ldregs(t, (const float*)W, brow0, 0); cvtwr(Bs[0], t); }
        else      stage16(Bs[0], (const ushort*)W, brow0, 0);
    }

    f32x4 acc[4][4] = {};
    int cur = 0;
    for (int kt = 0; kt < 32; ++kt) {
        __syncthreads();
        const bool pf = (kt < 31);
        const int  kn = (kt + 1) * 32;
        float4v ra[4], rb[4];
        if (pf) {
            if (af32) ldregs(ra, (const float*)A, arow0, kn);
            else      stage16(As[cur ^ 1], (const ushort*)A, arow0, kn);
            if (wf32) ldregs(rb, (const float*)W, brow0, kn);
            else      stage16(Bs[cur ^ 1], (const ushort*)W, brow0, kn);
        }
        bf16x8 fa[4], fb[4];
#pragma unroll
        for (int mi = 0; mi < 4; ++mi)
            fa[mi] = ld8(&As[cur][(wr * 64 + mi * 16 + l16) * 32 + quad * 8]);
#pragma unroll
        for (int ni = 0; ni < 4; ++ni)
            fb[ni] = ld8(&Bs[cur][(wc * 64 + ni * 16 + l16) * 32 + quad * 8]);
#pragma unroll
        for (int mi = 0; mi < 4; ++mi)
#pragma unroll
            for (int ni = 0; ni < 4; ++ni)
                acc[mi][ni] = __builtin_amdgcn_mfma_f32_16x16x32_bf16(fa[mi], fb[ni], acc[mi][ni], 0, 0, 0);
        if (pf) {
            if (af32) cvtwr(As[cur ^ 1], ra);
            if (wf32) cvtwr(Bs[cur ^ 1], rb);
        }
        cur ^= 1;
    }

    const bool of32 = OUTF && f32m;
    const int colbase = nb * 128 + wc * 64;
    float bv[4];
#pragma unroll
    for (int ni = 0; ni < 4; ++ni) {
        const int cg = colbase + ni * 16 + l16;
        bv[ni] = f32m ? ((const float*)bias)[cg] : bf2f(((const ushort*)bias)[cg]);
    }
    const int rowb = mb * 128 + wr * 64 + quad * 4;
#pragma unroll
    for (int mi = 0; mi < 4; ++mi) {
#pragma unroll
        for (int r = 0; r < 4; ++r) {
            const int rowg = rowb + mi * 16 + r;
            float v[4];
#pragma unroll
            for (int ni = 0; ni < 4; ++ni) v[ni] = acc[mi][ni][r] + bv[ni];
            if constexpr (EPI == 1 || EPI == 3) {
#pragma unroll
                for (int t = 0; t < 2; ++t) {
                    const size_t ci = (size_t)rowg * 64 + t * 16 + l16;
                    const float c = f32m ? ((const float*)rc)[ci] : bf2f(((const ushort*)rc)[ci]);
                    const float s = f32m ? ((const float*)rs)[ci] : bf2f(((const ushort*)rs)[ci]);
                    const float x1 = v[t], x2 = v[t + 2];
                    v[t]     = x1 * c - x2 * s;
                    v[t + 2] = x2 * c + x1 * s;
                }
                if constexpr (EPI == 3) {
#pragma unroll
                    for (int t = 0; t < 4; ++t) v[t] *= 0.125f;
                }
            } else if constexpr (EPI == 2) {
#pragma unroll
                for (int t = 0; t < 4; ++t) v[t] = 1.0f / (1.0f + __expf(-v[t]));
            }
#pragma unroll
            for (int ni = 0; ni < 4; ++ni) {
                const size_t idx = (size_t)rowg * Nd + colbase + ni * 16 + l16;
                if (of32) ((float*)C)[idx] = v[ni];
                else      ((ushort*)C)[idx] = f2bf(v[ni]);
            }
        }
    }
}

// ---------------------------------------------------------------------------
// Fused QKVG projection: one N=4096 GEMM over concatenated W (wb[0..3]
// contiguous). Grid 2048 -> 8 blocks/CU issued: barrier-drain stalls hide
// behind co-resident blocks (the N=1024 kernels ran 2/CU).
// Block decode: xcd=bid&7 (XCD-chunk), mb-inner so each XCD keeps its 2MB
// A-slice + current W panel in L2. seg = nb>>3 selects A src, bias, dst, EPI.
// ---------------------------------------------------------------------------
__global__ __launch_bounds__(256) void gemm_qkvg(
    const ushort* __restrict__ qbf, const ushort* __restrict__ kbf,
    const ushort* __restrict__ vbf, const ushort* __restrict__ Wcat,
    const void* __restrict__ bq, const void* __restrict__ bk,
    const void* __restrict__ bv_, const void* __restrict__ bg,
    const void* __restrict__ rc, const void* __restrict__ rs,
    ushort* __restrict__ Qp, ushort* __restrict__ Kp,
    ushort* __restrict__ Vp, ushort* __restrict__ Gt,
    const int* __restrict__ flag)
{
    constexpr int Kd = 1024;
    const bool f32m = (*flag != 0);
    const int tid  = threadIdx.x;
    const int xcd  = blockIdx.x & 7;
    const int rr   = blockIdx.x >> 3;        // 0..255
    const int mb   = xcd * 8 + (rr & 7);     // 0..63 (XCD-chunked, inner)
    const int nb   = rr >> 3;                // 0..31 (outer: W panel streams)
    const int seg  = nb >> 3;                // 0:Q 1:K 2:V 3:G
    const ushort* A   = seg == 0 ? qbf : seg == 1 ? kbf : seg == 2 ? vbf : qbf;
    const void* bias  = seg == 0 ? bq : seg == 1 ? bk : seg == 2 ? bv_ : bg;
    ushort* C         = seg == 0 ? Qp : seg == 1 ? Kp : seg == 2 ? Vp : Gt;

    const int wave = tid >> 6;
    const int lane = tid & 63;
    const int quad = lane >> 4;
    const int l16  = lane & 15;
    const int wr   = wave >> 1;
    const int wc   = wave & 1;

    __shared__ __align__(16) ushort As[2][128 * 32];
    __shared__ __align__(16) ushort Bs[2][128 * 32];

    const int arow0 = mb * 128;
    const int brow0 = nb * 128;               // rows of Wcat[4096][1024]

    auto stage16 = [&](ushort* lds, const ushort* src, int row0, int k0) {
#pragma unroll
        for (int j = 0; j < 2; ++j) {
            const int c = j * 256 + tid;
            glds16(src + (size_t)(row0 + (c >> 2)) * Kd + k0 + (c & 3) * 8, &lds[c * 8]);
        }
    };

    stage16(As[0], A, arow0, 0);
    stage16(Bs[0], Wcat, brow0, 0);

    f32x4 acc[4][4] = {};
    int cur = 0;
    for (int kt = 0; kt < 32; ++kt) {
        __syncthreads();
        if (kt < 31) {
            const int kn = (kt + 1) * 32;
            stage16(As[cur ^ 1], A, arow0, kn);
            stage16(Bs[cur ^ 1], Wcat, brow0, kn);
        }
        bf16x8 fa[4], fb[4];
#pragma unroll
        for (int mi = 0; mi < 4; ++mi)
            fa[mi] = ld8(&As[cur][(wr * 64 + mi * 16 + l16) * 32 + quad * 8]);
#pragma unroll
        for (int ni = 0; ni < 4; ++ni)
            fb[ni] = ld8(&Bs[cur][(wc * 64 + ni * 16 + l16) * 32 + quad * 8]);
#pragma unroll
        for (int mi = 0; mi < 4; ++mi)
#pragma unroll
            for (int ni = 0; ni < 4; ++ni)
                acc[mi][ni] = __builtin_amdgcn_mfma_f32_16x16x32_bf16(fa[mi], fb[ni], acc[mi][ni], 0, 0, 0);
        cur ^= 1;
    }

    const int colbase = (nb & 7) * 128 + wc * 64;   // column in the 1024-wide output
    float bv[4];
#pragma unroll
    for (int ni = 0; ni < 4; ++ni) {
        const int cg = colbase + ni * 16 + l16;
        bv[ni] = f32m ? ((const float*)bias)[cg] : bf2f(((const ushort*)bias)[cg]);
    }
    const int rowb = mb * 128 + wr * 64 + quad * 4;
#pragma unroll
    for (int mi = 0; mi < 4; ++mi) {
#pragma unroll
        for (int r = 0; r < 4; ++r) {
            const int rowg = rowb + mi * 16 + r;    // == b*1024 + pos
            float v[4];
#pragma unroll
            for (int ni = 0; ni < 4; ++ni) v[ni] = acc[mi][ni][r] + bv[ni];
            if (seg <= 1) {                          // RoPE (Q also pre-scaled)
#pragma unroll
                for (int t = 0; t < 2; ++t) {
                    const size_t ci = (size_t)rowg * 64 + t * 16 + l16;
                    const float c = f32m ? ((const float*)rc)[ci] : bf2f(((const ushort*)rc)[ci]);
                    const float s = f32m ? ((const float*)rs)[ci] : bf2f(((const ushort*)rs)[ci]);
                    const float x1 = v[t], x2 = v[t + 2];
                    v[t]     = x1 * c - x2 * s;
                    v[t + 2] = x2 * c + x1 * s;
                }
                if (seg == 0) {
#pragma unroll
                    for (int t = 0; t < 4; ++t) v[t] *= 0.125f;
                }
            } else if (seg == 3) {                   // sigmoid gate
#pragma unroll
                for (int t = 0; t < 4; ++t) v[t] = 1.0f / (1.0f + __expf(-v[t]));
            }
#pragma unroll
            for (int ni = 0; ni < 4; ++ni) {
                const size_t idx = (size_t)rowg * 1024 + colbase + ni * 16 + l16;
                C[idx] = f2bf(v[ni]);
            }
        }
    }
}

// ---------------------------------------------------------------------------
// Per-batch transpose: Vp[b*1024 + pos][col] -> Vt[b*1024 + col][pos]
// ---------------------------------------------------------------------------
__global__ __launch_bounds__(256) void transpose_vh(
    const ushort* __restrict__ Vp, ushort* __restrict__ Vt)
{
    const int bb = blockIdx.x >> 8;
    const int pr = (blockIdx.x >> 4) & 15;
    const int cr = blockIdx.x & 15;
    __shared__ ushort t[64 * 65];
    const int tid = threadIdx.x;
    {
        const int r = tid >> 3, c8 = (tid & 7) * 8;
#pragma unroll
        for (int hh = 0; hh < 2; ++hh) {
            const int rr = r + hh * 32;
            const ushort8 v = *(const ushort8*)(Vp + ((size_t)(bb * 1024 + pr * 64 + rr)) * 1024 + cr * 64 + c8);
#pragma unroll
            for (int i = 0; i < 8; ++i) t[rr * 65 + c8 + i] = v[i];
        }
    }
    __syncthreads();
    {
        const int c = tid >> 2, p0 = (tid & 3) * 16;
        ushort8 o0, o1;
#pragma unroll
        for (int i = 0; i < 8; ++i) {
            o0[i] = t[(p0 + i) * 65 + c];
            o1[i] = t[(p0 + 8 + i) * 65 + c];
        }
        ushort* dst = Vt + ((size_t)(bb * 1024 + cr * 64 + c)) * 1024 + pr * 64 + p0;
        *(ushort8*)dst       = o0;
        *(ushort8*)(dst + 8) = o1;
    }
}

// ---------------------------------------------------------------------------
// Flash attention v6: as v5 but the per-iter wait chain is halved -- both
// u-subtiles' softmax+P-writes complete first, then ONE lgkmcnt(0), then a
// single 16-MFMA PV cluster. Ps doubled to per-(wave,u).
// ---------------------------------------------------------------------------
__global__ __launch_bounds__(512) void attn_kernel(
    const ushort* __restrict__ Qp, const ushort* __restrict__ Kp,
    const ushort* __restrict__ Vt, const ushort* __restrict__ G,
    const unsigned char* __restrict__ mask, ushort* __restrict__ O)
{
    // grid 512 = 8 XCD x 64; each XCD owns one batch (K/V L2-resident).
    const int swz = (blockIdx.x & 7) * 64 + (blockIdx.x >> 3);
    const int qb = swz & 3;
    const int h  = (swz >> 2) & 15;
    const int b  = swz >> 6;
    const int tid  = threadIdx.x;
    const int wave = tid >> 6;
    const int lane = tid & 63;
    const int quad = lane >> 4;
    const int l16  = lane & 15;
    const size_t Dm = 1024;

    __shared__ __align__(16) ushort Ks[2][64 * 64];
    __shared__ __align__(16) ushort Vs[2][64 * 64];
    __shared__ __align__(16) ushort Ps[8][2][16 * 72];
    __shared__ __align__(16) unsigned char Ms[1024];

    const int q0 = qb * 256 + wave * 32;
    bf16x8 qa[2][2];
#pragma unroll
    for (int u = 0; u < 2; ++u) {
        const ushort* Qb = Qp + ((size_t)b * 1024 + q0 + u * 16 + l16) * Dm + h * 64 + quad * 8;
        qa[u][0] = ld8(Qb);
        qa[u][1] = ld8(Qb + 32);
    }
    const ushort* Kbase = Kp + ((size_t)b * 1024) * Dm + h * 64;
    const ushort* Vbase = Vt + ((size_t)b * 1024 + h * 64) * 1024;

    auto stageK = [&](ushort* lds, int k0) {
        const int row = tid >> 3;
        const int col8 = (tid & 7) ^ (row & 7);
        glds16(Kbase + (size_t)(k0 + row) * Dm + col8 * 8, &lds[tid * 8]);
    };
    auto stageV = [&](ushort* lds, int k0) {
        const int row = tid >> 3;
        const int col8 = (tid & 7) ^ (row & 7);
        glds16(Vbase + (size_t)row * 1024 + k0 + col8 * 8, &lds[tid * 8]);
    };

    stageK(Ks[0], 0);
    stageV(Vs[0], 0);
    if (tid < 256)
        ((unsigned int*)Ms)[tid] = ((const unsigned int*)(mask + (size_t)b * 1024))[tid];
    __syncthreads();
    bool anym;
    {
        const unsigned long long* M8 = (const unsigned long long*)Ms;
        anym = __any((M8[lane] | M8[lane + 64]) != 0ULL);
    }

    float m_r[2] = { -3.0e38f, -3.0e38f };
    float l_r[2] = { 0.0f, 0.0f };
    f32x4 o[2][4] = {};

    int cur = 0;
    for (int kt = 0; kt < 16; ++kt) {
        __syncthreads();
        if (kt < 15) {
            stageK(Ks[cur ^ 1], (kt + 1) * 64);
            stageV(Vs[cur ^ 1], (kt + 1) * 64);
        }
        const int k0 = kt * 64;
        // --- swapped QK^T: row(quad*4+r)=key, col(l16)=q-row
        bf16x8 kf0[4], kf1[4];
#pragma unroll
        for (int ct = 0; ct < 4; ++ct) {
            const int row = ct * 16 + l16;
            kf0[ct] = ld8(&Ks[cur][row * 64 + ((quad)     ^ (row & 7)) * 8]);
            kf1[ct] = ld8(&Ks[cur][row * 64 + ((4 + quad) ^ (row & 7)) * 8]);
        }
        f32x4 s[2][4] = {};
        __builtin_amdgcn_s_setprio(1);
#pragma unroll
        for (int u = 0; u < 2; ++u)
#pragma unroll
            for (int ct = 0; ct < 4; ++ct) {
                s[u][ct] = __builtin_amdgcn_mfma_f32_16x16x32_bf16(kf0[ct], qa[u][0], s[u][ct], 0, 0, 0);
                s[u][ct] = __builtin_amdgcn_mfma_f32_16x16x32_bf16(kf1[ct], qa[u][1], s[u][ct], 0, 0, 0);
            }
        __builtin_amdgcn_s_setprio(0);
        // --- V fragments (shared by both u)
        bf16x8 vf[4][2];
#pragma unroll
        for (int t = 0; t < 4; ++t) {
            const int row = t * 16 + l16;
#pragma unroll
            for (int kk = 0; kk < 2; ++kk)
                vf[t][kk] = ld8(&Vs[cur][row * 64 + (((kk * 4 + quad) ^ (row & 7))) * 8]);
        }
        // --- softmax for BOTH u, then both P-writes ---
#pragma unroll
        for (int u = 0; u < 2; ++u) {
            float sv[4][4];
#pragma unroll
            for (int ct = 0; ct < 4; ++ct)
#pragma unroll
                for (int r = 0; r < 4; ++r) sv[ct][r] = s[u][ct][r];
            if (anym) {
#pragma unroll
                for (int ct = 0; ct < 4; ++ct) {
                    const unsigned int mb4 = *(const unsigned int*)&Ms[k0 + ct * 16 + quad * 4];
#pragma unroll
                    for (int r = 0; r < 4; ++r)
                        if ((mb4 >> (8 * r)) & 0xffu) sv[ct][r] = -1e30f;
                }
            }
            float mxv = sv[0][0];
#pragma unroll
            for (int ct = 0; ct < 4; ++ct)
#pragma unroll
                for (int r = 0; r < 4; ++r) mxv = fmaxf(mxv, sv[ct][r]);
            mxv = fmaxf(mxv, __shfl_xor(mxv, 16, 64));
            mxv = fmaxf(mxv, __shfl_xor(mxv, 32, 64));
            if (__any(mxv > m_r[u] + 8.0f)) {        // rare: real max growth
                const float mnew  = fmaxf(m_r[u], mxv);
                const float alpha = __expf(m_r[u] - mnew);
                l_r[u] *= alpha;
                m_r[u]  = mnew;
#pragma unroll
                for (int r = 0; r < 4; ++r) {
                    const float ar = __shfl(alpha, quad * 4 + r, 64);
#pragma unroll
                    for (int t = 0; t < 4; ++t) o[u][t][r] *= ar;
                }
            }
            float ls = 0.0f;
            bf16x4 w[4];
#pragma unroll
            for (int ct = 0; ct < 4; ++ct)
#pragma unroll
                for (int r = 0; r < 4; ++r) {
                    const float pv = __expf(sv[ct][r] - m_r[u]);   // bounded by e^8
                    ls += pv;
                    w[ct][r] = (__bf16)pv;
                }
            l_r[u] += ls;
#pragma unroll
            for (int ct = 0; ct < 4; ++ct)
                *(bf16x4*)&Ps[wave][u][l16 * 72 + ct * 16 + quad * 4] = w[ct];
        }
        // --- ONE wait, then a single 16-MFMA PV cluster ---
        asm volatile("s_waitcnt lgkmcnt(0)" ::: "memory");
        __builtin_amdgcn_sched_barrier(0);
        bf16x8 pa[2][2];
#pragma unroll
        for (int u = 0; u < 2; ++u) {
            pa[u][0] = ld8(&Ps[wave][u][l16 * 72 + quad * 8]);
            pa[u][1] = ld8(&Ps[wave][u][l16 * 72 + 32 + quad * 8]);
        }
        __builtin_amdgcn_s_setprio(1);
#pragma unroll
        for (int u = 0; u < 2; ++u)
#pragma unroll
            for (int t = 0; t < 4; ++t) {
                o[u][t] = __builtin_amdgcn_mfma_f32_16x16x32_bf16(pa[u][0], vf[t][0], o[u][t], 0, 0, 0);
                o[u][t] = __builtin_amdgcn_mfma_f32_16x16x32_bf16(pa[u][1], vf[t][1], o[u][t], 0, 0, 0);
            }
        __builtin_amdgcn_s_setprio(0);
        cur ^= 1;
    }
    // epilogue: reduce l across quads once, redistribute, normalize, gate, store
#pragma unroll
    for (int u = 0; u < 2; ++u) {
        float lt = l_r[u];
        lt += __shfl_xor(lt, 16, 64);
        lt += __shfl_xor(lt, 32, 64);
        const int rowg0 = b * 1024 + q0 + u * 16 + quad * 4;
#pragma unroll
        for (int r = 0; r < 4; ++r) {
            const float inv = 1.0f / __shfl(lt, quad * 4 + r, 64);
#pragma unroll
            for (int t = 0; t < 4; ++t) {
                const size_t idx = (size_t)(rowg0 + r) * Dm + h * 64 + t * 16 + l16;
                O[idx] = f2bf(o[u][t][r] * inv * bf2f(G[idx]));
            }
        }
    }
}

extern "C" void kernel_launch(void* const* d_in, const int* in_sizes, int n_in,
                              void* d_out, int out_size, void* d_ws, size_t ws_size,
                              hipStream_t stream)
{
    const void* query = d_in[0];
    const void* key   = d_in[1];
    const void* value = d_in[2];
    const void* Wq    = d_in[3];
    const void* bq    = d_in[4];
    const void* Wk    = d_in[5];
    const void* bk    = d_in[6];
    const void* Wv    = d_in[7];
    const void* bv    = d_in[8];
    const void* Wg    = d_in[9];
    const void* bg    = d_in[10];
    const void* Wo    = d_in[11];
    const void* bo    = d_in[12];
    const void* rc    = d_in[13];
    const void* rs    = d_in[14];
    const unsigned char* mask = (const unsigned char*)d_in[15];

    char* ws = (char*)d_ws;
    const size_t MB = (size_t)1 << 20;
    const size_t MB16 = 16 * MB;
    const bool big = ws_size >= 139 * MB;

    ushort* Qp = (ushort*)(ws);
    ushort* Kp = (ushort*)(ws + 1 * MB16);
    ushort* Vp = (ushort*)(ws + 2 * MB16);
    ushort* Gt = (ushort*)(ws + 3 * MB16);
    ushort* Vt = (ushort*)(ws + 4 * MB16);
    ushort* Ag = (ushort*)(ws + 2 * MB16);       // alias Vp: dead after transpose
    int*  flag = (int*)(ws + (big ? 138 * MB : 5 * MB16));

    const dim3 gb(512), gt(256);
    hipLaunchKernelGGL(sniff_kernel, dim3(1), dim3(64), 0, stream, (const ushort*)query, flag);

    if (big) {
        ushort* qbf = (ushort*)(ws + 80 * MB);
        ushort* kbf = (ushort*)(ws + 96 * MB);
        ushort* vbf = (ushort*)(ws + 112 * MB);
        ushort* wcat = (ushort*)(ws + 128 * MB); // wb[0..3] contiguous = Wcat[4096][1024]
        ushort* wb[5];
        for (int i = 0; i < 5; ++i) wb[i] = wcat + (size_t)i * 1024 * 1024;

        hipLaunchKernelGGL(cvt_qkv, dim3(3 * 2048), dim3(256), 0, stream,
                           query, key, value, qbf, kbf, vbf, flag);
        hipLaunchKernelGGL(cvt_w5, dim3(5 * 512), dim3(256), 0, stream,
                           Wq, Wk, Wv, Wg, Wo, wb[0], wb[1], wb[2], wb[3], wb[4], flag);

        hipLaunchKernelGGL(gemm_qkvg, dim3(2048), dim3(256), 0, stream,
                           qbf, kbf, vbf, wcat, bq, bk, bv, bg, rc, rs,
                           Qp, Kp, Vp, Gt, flag);

        hipLaunchKernelGGL(transpose_vh, dim3(2048), dim3(256), 0, stream, Vp, Vt);
        hipLaunchKernelGGL(attn_kernel,  dim3(512), dim3(512), 0, stream, Qp, Kp, Vt, Gt, mask, Ag);

        hipLaunchKernelGGL((gemm_bt<0,1,1,1>), gb, gt, 0, stream, Ag, wb[4], bo, rc, rs, d_out, flag);
    } else {
        hipLaunchKernelGGL((gemm_bt<3,0,0,0>), gb, gt, 0, stream, query, Wq, bq, rc, rs, Qp, flag);
        hipLaunchKernelGGL((gemm_bt<1,0,0,0>), gb, gt, 0, stream, key,   Wk, bk, rc, rs, Kp, flag);
        hipLaunchKernelGGL((gemm_bt<0,0,0,0>), gb, gt, 0, stream, value, Wv, bv, rc, rs, Vp, flag);
        hipLaunchKernelGGL((gemm_bt<2,0,0,0>), gb, gt, 0, stream, query, Wg, bg, rc, rs, Gt, flag);

        hipLaunchKernelGGL(transpose_vh, dim3(2048), dim3(256), 0, stream, Vp, Vt);
        hipLaunchKernelGGL(attn_kernel,  dim3(512), dim3(512), 0, stream, Qp, Kp, Vt, Gt, mask, Ag);

        hipLaunchKernelGGL((gemm_bt<0,1,0,1>), gb, gt, 0, stream, Ag, Wo, bo, rc, rs, d_out, flag);
    }
}

// Round 9
// 387.912 us; speedup vs baseline: 1.6968x; 1.0192x over previous
//
#include <hip/hip_runtime.h>

using ushort  = unsigned short;
using bf16x8  = __attribute__((ext_vector_type(8))) __bf16;
using bf16x4  = __attribute__((ext_vector_type(4))) __bf16;
using ushort8 = __attribute__((ext_vector_type(8))) unsigned short;
using f32x4   = __attribute__((ext_vector_type(4))) float;
using float4v = __attribute__((ext_vector_type(4))) float;

__device__ __forceinline__ float bf2f(ushort u) {
    union { unsigned int i; float f; } v; v.i = ((unsigned int)u) << 16; return v.f;
}
__device__ __forceinline__ ushort f2bf(float f) {
    union { float f; unsigned int i; } v; v.f = f;
    unsigned int r = v.i + 0x7FFFu + ((v.i >> 16) & 1u);
    return (ushort)(r >> 16);
}
__device__ __forceinline__ bf16x8 ld8(const ushort* p) {
    return __builtin_bit_cast(bf16x8, *(const ushort8*)p);
}
// async global->LDS, 16B per lane (dest = wave-uniform base + lane*16)
__device__ __forceinline__ void glds16(const void* g, void* l) {
    __builtin_amdgcn_global_load_lds(
        (const __attribute__((address_space(1))) unsigned int*)g,
        (__attribute__((address_space(3))) unsigned int*)l, 16, 0, 0);
}

// ---------------------------------------------------------------------------
// Dtype sniffer: bf16 (flag=0) vs f32 (flag=1) storage, decided from `query`.
// ---------------------------------------------------------------------------
__global__ void sniff_kernel(const ushort* __restrict__ q, int* __restrict__ flag) {
    const int lane = threadIdx.x;              // 64 threads, 1 block
    float mx = 0.0f;
    for (int i = lane; i < 512; i += 64) {
        float v = bf2f(q[2 * i]);              // even halfword
        mx = fmaxf(mx, fabsf(v));
    }
#pragma unroll
    for (int off = 32; off >= 1; off >>= 1) mx = fmaxf(mx, __shfl_xor(mx, off, 64));
    if (lane == 0) *flag = (mx > 1.0e6f) ? 1 : 0;
}

// ---------------------------------------------------------------------------
// Convert-or-copy 8 elements at vec8 index i.
// ---------------------------------------------------------------------------
__device__ __forceinline__ void cvt8(const void* src, ushort* dst, int i, bool f32m) {
    if (f32m) {
        const float4v a = ((const float4v*)src)[2 * i];
        const float4v b = ((const float4v*)src)[2 * i + 1];
        bf16x8 o;
#pragma unroll
        for (int j = 0; j < 4; ++j) { o[j] = (__bf16)a[j]; o[j + 4] = (__bf16)b[j]; }
        ((ushort8*)dst)[i] = __builtin_bit_cast(ushort8, o);
    } else {
        ((ushort8*)dst)[i] = ((const ushort8*)src)[i];
    }
}

// q/k/v activations: 3 segments x 1M vec8, grid 3*2048
__global__ __launch_bounds__(256) void cvt_qkv(
    const void* __restrict__ s0, const void* __restrict__ s1, const void* __restrict__ s2,
    ushort* __restrict__ d0, ushort* __restrict__ d1, ushort* __restrict__ d2,
    const int* __restrict__ flag)
{
    const bool f32m = (*flag != 0);
    const int seg = blockIdx.x >> 11;
    const void* src = seg == 0 ? s0 : (seg == 1 ? s1 : s2);
    ushort*    dst = seg == 0 ? d0 : (seg == 1 ? d1 : d2);
    for (int i = (blockIdx.x & 2047) * 256 + threadIdx.x; i < 1048576; i += 2048 * 256)
        cvt8(src, dst, i, f32m);
}
// 5 weight matrices: 5 segments x 128K vec8, grid 5*512
__global__ __launch_bounds__(256) void cvt_w5(
    const void* __restrict__ s0, const void* __restrict__ s1, const void* __restrict__ s2,
    const void* __restrict__ s3, const void* __restrict__ s4,
    ushort* __restrict__ d0, ushort* __restrict__ d1, ushort* __restrict__ d2,
    ushort* __restrict__ d3, ushort* __restrict__ d4,
    const int* __restrict__ flag)
{
    const bool f32m = (*flag != 0);
    const int seg = blockIdx.x >> 9;
    const void* src = seg == 0 ? s0 : seg == 1 ? s1 : seg == 2 ? s2 : seg == 3 ? s3 : s4;
    ushort*    dst = seg == 0 ? d0 : seg == 1 ? d1 : seg == 2 ? d2 : seg == 3 ? d3 : d4;
    cvt8(src, dst, (blockIdx.x & 511) * 256 + threadIdx.x, f32m);
}

// LDS chunk swizzle for the [128][32-ushort] GEMM tiles: slot s of row r
// holds global 16B-chunk c = s ^ ((r>>1)&3). 16 lanes reading fixed c at
// rows 0..15 then span all 8 bank-groups (2 lanes each = conflict-free),
// vs 8-way conflict for the linear layout.
#define CHUNK_SWZ(r, s) ((s) ^ (((r) >> 1) & 3))

// ---------------------------------------------------------------------------
// Generic GEMM (small-ws fallback and final projection):
// C[M=8192, N=1024] = A * W^T + bias. 128x128 tile, BK=32, 4 waves, dbuf LDS.
// EPI 0: none  1: RoPE  2: sigmoid  3: RoPE * 0.125
// ---------------------------------------------------------------------------
template<int EPI, int ABF16, int WBF16, int OUTF>
__global__ __launch_bounds__(256) void gemm_bt(
    const void* __restrict__ A, const void* __restrict__ W,
    const void* __restrict__ bias,
    const void* __restrict__ rc, const void* __restrict__ rs,
    void* __restrict__ C, const int* __restrict__ flag)
{
    constexpr int Kd = 1024, Nd = 1024;
    const bool f32m = (*flag != 0);
    const bool af32 = f32m && !ABF16;
    const bool wf32 = f32m && !WBF16;

    const int tid  = threadIdx.x;
    const int swz  = (blockIdx.x & 7) * 64 + (blockIdx.x >> 3);
    const int nb   = swz & 7;
    const int mb   = swz >> 3;
    const int wave = tid >> 6;
    const int lane = tid & 63;
    const int quad = lane >> 4;
    const int l16  = lane & 15;
    const int wr   = wave >> 1;
    const int wc   = wave & 1;

    __shared__ __align__(16) ushort As[2][128 * 32];
    __shared__ __align__(16) ushort Bs[2][128 * 32];

    const int arow0 = mb * 128;
    const int brow0 = nb * 128;

    auto ldregs = [&](float4v r[4], const float* src, int row0, int k0) {
#pragma unroll
        for (int j = 0; j < 2; ++j) {
            const int c = j * 256 + tid;
            const float* gp = src + (size_t)(row0 + (c >> 2)) * Kd + k0 + (c & 3) * 8;
            r[2 * j]     = *(const float4v*)gp;
            r[2 * j + 1] = *(const float4v*)(gp + 4);
        }
    };
    // write chunk (c&3) of row (c>>2) at swizzled LDS slot
    auto cvtwr = [&](ushort* lds, const float4v r[4]) {
#pragma unroll
        for (int j = 0; j < 2; ++j) {
            const int c = j * 256 + tid;
            const int row = c >> 2;
            const int sl  = CHUNK_SWZ(row, c & 3);
            bf16x8 o;
#pragma unroll
            for (int i = 0; i < 4; ++i) {
                o[i]     = (__bf16)r[2 * j][i];
                o[i + 4] = (__bf16)r[2 * j + 1][i];
            }
            *(ushort8*)&lds[row * 32 + sl * 8] = __builtin_bit_cast(ushort8, o);
        }
    };
    // linear LDS dest (slot t), pre-swizzled global source chunk
    auto stage16 = [&](ushort* lds, const ushort* src, int row0, int k0) {
#pragma unroll
        for (int j = 0; j < 2; ++j) {
            const int t = j * 256 + tid;
            const int row = t >> 2;
            const int c   = CHUNK_SWZ(row, t & 3);
            glds16(src + (size_t)(row0 + row) * Kd + k0 + c * 8, &lds[t * 8]);
        }
    };

    {
        float4v t[4];
        if (af32) { ldregs(t, (const float*)A, arow0, 0); cvtwr(As[0], t); }
        else      stage16(As[0], (const ushort*)A, arow0, 0);
        if (wf32) { ldregs(t, (const float*)W, brow0, 0); cvtwr(Bs[0], t); }
        else      stage16(Bs[0], (const ushort*)W, brow0, 0);
    }

    f32x4 acc[4][4] = {};
    int cur = 0;
    for (int kt = 0; kt < 32; ++kt) {
        __syncthreads();
        const bool pf = (kt < 31);
        const int  kn = (kt + 1) * 32;
        float4v ra[4], rb[4];
        if (pf) {
            if (af32) ldregs(ra, (const float*)A, arow0, kn);
            else      stage16(As[cur ^ 1], (const ushort*)A, arow0, kn);
            if (wf32) ldregs(rb, (const float*)W, brow0, kn);
            else      stage16(Bs[cur ^ 1], (const ushort*)W, brow0, kn);
        }
        bf16x8 fa[4], fb[4];
#pragma unroll
        for (int mi = 0; mi < 4; ++mi) {
            const int row = wr * 64 + mi * 16 + l16;
            fa[mi] = ld8(&As[cur][row * 32 + CHUNK_SWZ(row, quad) * 8]);
        }
#pragma unroll
        for (int ni = 0; ni < 4; ++ni) {
            const int row = wc * 64 + ni * 16 + l16;
            fb[ni] = ld8(&Bs[cur][row * 32 + CHUNK_SWZ(row, quad) * 8]);
        }
#pragma unroll
        for (int mi = 0; mi < 4; ++mi)
#pragma unroll
            for (int ni = 0; ni < 4; ++ni)
                acc[mi][ni] = __builtin_amdgcn_mfma_f32_16x16x32_bf16(fa[mi], fb[ni], acc[mi][ni], 0, 0, 0);
        if (pf) {
            if (af32) cvtwr(As[cur ^ 1], ra);
            if (wf32) cvtwr(Bs[cur ^ 1], rb);
        }
        cur ^= 1;
    }

    const bool of32 = OUTF && f32m;
    const int colbase = nb * 128 + wc * 64;
    float bv[4];
#pragma unroll
    for (int ni = 0; ni < 4; ++ni) {
        const int cg = colbase + ni * 16 + l16;
        bv[ni] = f32m ? ((const float*)bias)[cg] : bf2f(((const ushort*)bias)[cg]);
    }
    const int rowb = mb * 128 + wr * 64 + quad * 4;
#pragma unroll
    for (int mi = 0; mi < 4; ++mi) {
#pragma unroll
        for (int r = 0; r < 4; ++r) {
            const int rowg = rowb + mi * 16 + r;
            float v[4];
#pragma unroll
            for (int ni = 0; ni < 4; ++ni) v[ni] = acc[mi][ni][r] + bv[ni];
            if constexpr (EPI == 1 || EPI == 3) {
#pragma unroll
                for (int t = 0; t < 2; ++t) {
                    const size_t ci = (size_t)rowg * 64 + t * 16 + l16;
                    const float c = f32m ? ((const float*)rc)[ci] : bf2f(((const ushort*)rc)[ci]);
                    const float s = f32m ? ((const float*)rs)[ci] : bf2f(((const ushort*)rs)[ci]);
                    const float x1 = v[t], x2 = v[t + 2];
                    v[t]     = x1 * c - x2 * s;
                    v[t + 2] = x2 * c + x1 * s;
                }
                if constexpr (EPI == 3) {
#pragma unroll
                    for (int t = 0; t < 4; ++t) v[t] *= 0.125f;
                }
            } else if constexpr (EPI == 2) {
#pragma unroll
                for (int t = 0; t < 4; ++t) v[t] = 1.0f / (1.0f + __expf(-v[t]));
            }
#pragma unroll
            for (int ni = 0; ni < 4; ++ni) {
                const size_t idx = (size_t)rowg * Nd + colbase + ni * 16 + l16;
                if (of32) ((float*)C)[idx] = v[ni];
                else      ((ushort*)C)[idx] = f2bf(v[ni]);
            }
        }
    }
}

// ---------------------------------------------------------------------------
// Fused QKVG projection: one N=4096 GEMM over concatenated W (wb[0..3]
// contiguous). Grid 2048 -> 8 blocks/CU issued. XCD-chunked mb-inner decode.
// seg = nb>>3 selects A src, bias, dst, epilogue. LDS chunk-swizzled (T2).
// ---------------------------------------------------------------------------
__global__ __launch_bounds__(256) void gemm_qkvg(
    const ushort* __restrict__ qbf, const ushort* __restrict__ kbf,
    const ushort* __restrict__ vbf, const ushort* __restrict__ Wcat,
    const void* __restrict__ bq, const void* __restrict__ bk,
    const void* __restrict__ bv_, const void* __restrict__ bg,
    const void* __restrict__ rc, const void* __restrict__ rs,
    ushort* __restrict__ Qp, ushort* __restrict__ Kp,
    ushort* __restrict__ Vp, ushort* __restrict__ Gt,
    const int* __restrict__ flag)
{
    constexpr int Kd = 1024;
    const bool f32m = (*flag != 0);
    const int tid  = threadIdx.x;
    const int xcd  = blockIdx.x & 7;
    const int rr   = blockIdx.x >> 3;        // 0..255
    const int mb   = xcd * 8 + (rr & 7);     // 0..63 (XCD-chunked, inner)
    const int nb   = rr >> 3;                // 0..31 (outer: W panel streams)
    const int seg  = nb >> 3;                // 0:Q 1:K 2:V 3:G
    const ushort* A   = seg == 0 ? qbf : seg == 1 ? kbf : seg == 2 ? vbf : qbf;
    const void* bias  = seg == 0 ? bq : seg == 1 ? bk : seg == 2 ? bv_ : bg;
    ushort* C         = seg == 0 ? Qp : seg == 1 ? Kp : seg == 2 ? Vp : Gt;

    const int wave = tid >> 6;
    const int lane = tid & 63;
    const int quad = lane >> 4;
    const int l16  = lane & 15;
    const int wr   = wave >> 1;
    const int wc   = wave & 1;

    __shared__ __align__(16) ushort As[2][128 * 32];
    __shared__ __align__(16) ushort Bs[2][128 * 32];

    const int arow0 = mb * 128;
    const int brow0 = nb * 128;               // rows of Wcat[4096][1024]

    auto stage16 = [&](ushort* lds, const ushort* src, int row0, int k0) {
#pragma unroll
        for (int j = 0; j < 2; ++j) {
            const int t = j * 256 + tid;
            const int row = t >> 2;
            const int c   = CHUNK_SWZ(row, t & 3);
            glds16(src + (size_t)(row0 + row) * Kd + k0 + c * 8, &lds[t * 8]);
        }
    };

    stage16(As[0], A, arow0, 0);
    stage16(Bs[0], Wcat, brow0, 0);

    f32x4 acc[4][4] = {};
    int cur = 0;
    for (int kt = 0; kt < 32; ++kt) {
        __syncthreads();
        if (kt < 31) {
            const int kn = (kt + 1) * 32;
            stage16(As[cur ^ 1], A, arow0, kn);
            stage16(Bs[cur ^ 1], Wcat, brow0, kn);
        }
        bf16x8 fa[4], fb[4];
#pragma unroll
        for (int mi = 0; mi < 4; ++mi) {
            const int row = wr * 64 + mi * 16 + l16;
            fa[mi] = ld8(&As[cur][row * 32 + CHUNK_SWZ(row, quad) * 8]);
        }
#pragma unroll
        for (int ni = 0; ni < 4; ++ni) {
            const int row = wc * 64 + ni * 16 + l16;
            fb[ni] = ld8(&Bs[cur][row * 32 + CHUNK_SWZ(row, quad) * 8]);
        }
#pragma unroll
        for (int mi = 0; mi < 4; ++mi)
#pragma unroll
            for (int ni = 0; ni < 4; ++ni)
                acc[mi][ni] = __builtin_amdgcn_mfma_f32_16x16x32_bf16(fa[mi], fb[ni], acc[mi][ni], 0, 0, 0);
        cur ^= 1;
    }

    const int colbase = (nb & 7) * 128 + wc * 64;   // column in the 1024-wide output
    float bv[4];
#pragma unroll
    for (int ni = 0; ni < 4; ++ni) {
        const int cg = colbase + ni * 16 + l16;
        bv[ni] = f32m ? ((const float*)bias)[cg] : bf2f(((const ushort*)bias)[cg]);
    }
    const int rowb = mb * 128 + wr * 64 + quad * 4;
#pragma unroll
    for (int mi = 0; mi < 4; ++mi) {
#pragma unroll
        for (int r = 0; r < 4; ++r) {
            const int rowg = rowb + mi * 16 + r;    // == b*1024 + pos
            float v[4];
#pragma unroll
            for (int ni = 0; ni < 4; ++ni) v[ni] = acc[mi][ni][r] + bv[ni];
            if (seg <= 1) {                          // RoPE (Q also pre-scaled)
#pragma unroll
                for (int t = 0; t < 2; ++t) {
                    const size_t ci = (size_t)rowg * 64 + t * 16 + l16;
                    const float c = f32m ? ((const float*)rc)[ci] : bf2f(((const ushort*)rc)[ci]);
                    const float s = f32m ? ((const float*)rs)[ci] : bf2f(((const ushort*)rs)[ci]);
                    const float x1 = v[t], x2 = v[t + 2];
                    v[t]     = x1 * c - x2 * s;
                    v[t + 2] = x2 * c + x1 * s;
                }
                if (seg == 0) {
#pragma unroll
                    for (int t = 0; t < 4; ++t) v[t] *= 0.125f;
                }
            } else if (seg == 3) {                   // sigmoid gate
#pragma unroll
                for (int t = 0; t < 4; ++t) v[t] = 1.0f / (1.0f + __expf(-v[t]));
            }
#pragma unroll
            for (int ni = 0; ni < 4; ++ni) {
                const size_t idx = (size_t)rowg * 1024 + colbase + ni * 16 + l16;
                C[idx] = f2bf(v[ni]);
            }
        }
    }
}

// ---------------------------------------------------------------------------
// Per-batch transpose: Vp[b*1024 + pos][col] -> Vt[b*1024 + col][pos]
// ---------------------------------------------------------------------------
__global__ __launch_bounds__(256) void transpose_vh(
    const ushort* __restrict__ Vp, ushort* __restrict__ Vt)
{
    const int bb = blockIdx.x >> 8;
    const int pr = (blockIdx.x >> 4) & 15;
    const int cr = blockIdx.x & 15;
    __shared__ ushort t[64 * 65];
    const int tid = threadIdx.x;
    {
        const int r = tid >> 3, c8 = (tid & 7) * 8;
#pragma unroll
        for (int hh = 0; hh < 2; ++hh) {
            const int rr = r + hh * 32;
            const ushort8 v = *(const ushort8*)(Vp + ((size_t)(bb * 1024 + pr * 64 + rr)) * 1024 + cr * 64 + c8);
#pragma unroll
            for (int i = 0; i < 8; ++i) t[rr * 65 + c8 + i] = v[i];
        }
    }
    __syncthreads();
    {
        const int c = tid >> 2, p0 = (tid & 3) * 16;
        ushort8 o0, o1;
#pragma unroll
        for (int i = 0; i < 8; ++i) {
            o0[i] = t[(p0 + i) * 65 + c];
            o1[i] = t[(p0 + 8 + i) * 65 + c];
        }
        ushort* dst = Vt + ((size_t)(bb * 1024 + cr * 64 + c)) * 1024 + pr * 64 + p0;
        *(ushort8*)dst       = o0;
        *(ushort8*)(dst + 8) = o1;
    }
}

// ---------------------------------------------------------------------------
// Flash attention v6: swapped QK^T, lane-local softmax, defer-max, one
// lgkmcnt per iter, 16-MFMA PV cluster. (Unchanged from R8.)
// ---------------------------------------------------------------------------
__global__ __launch_bounds__(512) void attn_kernel(
    const ushort* __restrict__ Qp, const ushort* __restrict__ Kp,
    const ushort* __restrict__ Vt, const ushort* __restrict__ G,
    const unsigned char* __restrict__ mask, ushort* __restrict__ O)
{
    // grid 512 = 8 XCD x 64; each XCD owns one batch (K/V L2-resident).
    const int swz = (blockIdx.x & 7) * 64 + (blockIdx.x >> 3);
    const int qb = swz & 3;
    const int h  = (swz >> 2) & 15;
    const int b  = swz >> 6;
    const int tid  = threadIdx.x;
    const int wave = tid >> 6;
    const int lane = tid & 63;
    const int quad = lane >> 4;
    const int l16  = lane & 15;
    const size_t Dm = 1024;

    __shared__ __align__(16) ushort Ks[2][64 * 64];
    __shared__ __align__(16) ushort Vs[2][64 * 64];
    __shared__ __align__(16) ushort Ps[8][2][16 * 72];
    __shared__ __align__(16) unsigned char Ms[1024];

    const int q0 = qb * 256 + wave * 32;
    bf16x8 qa[2][2];
#pragma unroll
    for (int u = 0; u < 2; ++u) {
        const ushort* Qb = Qp + ((size_t)b * 1024 + q0 + u * 16 + l16) * Dm + h * 64 + quad * 8;
        qa[u][0] = ld8(Qb);
        qa[u][1] = ld8(Qb + 32);
    }
    const ushort* Kbase = Kp + ((size_t)b * 1024) * Dm + h * 64;
    const ushort* Vbase = Vt + ((size_t)b * 1024 + h * 64) * 1024;

    auto stageK = [&](ushort* lds, int k0) {
        const int row = tid >> 3;
        const int col8 = (tid & 7) ^ (row & 7);
        glds16(Kbase + (size_t)(k0 + row) * Dm + col8 * 8, &lds[tid * 8]);
    };
    auto stageV = [&](ushort* lds, int k0) {
        const int row = tid >> 3;
        const int col8 = (tid & 7) ^ (row & 7);
        glds16(Vbase + (size_t)row * 1024 + k0 + col8 * 8, &lds[tid * 8]);
    };

    stageK(Ks[0], 0);
    stageV(Vs[0], 0);
    if (tid < 256)
        ((unsigned int*)Ms)[tid] = ((const unsigned int*)(mask + (size_t)b * 1024))[tid];
    __syncthreads();
    bool anym;
    {
        const unsigned long long* M8 = (const unsigned long long*)Ms;
        anym = __any((M8[lane] | M8[lane + 64]) != 0ULL);
    }

    float m_r[2] = { -3.0e38f, -3.0e38f };
    float l_r[2] = { 0.0f, 0.0f };
    f32x4 o[2][4] = {};

    int cur = 0;
    for (int kt = 0; kt < 16; ++kt) {
        __syncthreads();
        if (kt < 15) {
            stageK(Ks[cur ^ 1], (kt + 1) * 64);
            stageV(Vs[cur ^ 1], (kt + 1) * 64);
        }
        const int k0 = kt * 64;
        // --- swapped QK^T: row(quad*4+r)=key, col(l16)=q-row
        bf16x8 kf0[4], kf1[4];
#pragma unroll
        for (int ct = 0; ct < 4; ++ct) {
            const int row = ct * 16 + l16;
            kf0[ct] = ld8(&Ks[cur][row * 64 + ((quad)     ^ (row & 7)) * 8]);
            kf1[ct] = ld8(&Ks[cur][row * 64 + ((4 + quad) ^ (row & 7)) * 8]);
        }
        f32x4 s[2][4] = {};
        __builtin_amdgcn_s_setprio(1);
#pragma unroll
        for (int u = 0; u < 2; ++u)
#pragma unroll
            for (int ct = 0; ct < 4; ++ct) {
                s[u][ct] = __builtin_amdgcn_mfma_f32_16x16x32_bf16(kf0[ct], qa[u][0], s[u][ct], 0, 0, 0);
                s[u][ct] = __builtin_amdgcn_mfma_f32_16x16x32_bf16(kf1[ct], qa[u][1], s[u][ct], 0, 0, 0);
            }
        __builtin_amdgcn_s_setprio(0);
        // --- V fragments (shared by both u)
        bf16x8 vf[4][2];
#pragma unroll
        for (int t = 0; t < 4; ++t) {
            const int row = t * 16 + l16;
#pragma unroll
            for (int kk = 0; kk < 2; ++kk)
                vf[t][kk] = ld8(&Vs[cur][row * 64 + (((kk * 4 + quad) ^ (row & 7))) * 8]);
        }
        // --- softmax for BOTH u, then both P-writes ---
#pragma unroll
        for (int u = 0; u < 2; ++u) {
            float sv[4][4];
#pragma unroll
            for (int ct = 0; ct < 4; ++ct)
#pragma unroll
                for (int r = 0; r < 4; ++r) sv[ct][r] = s[u][ct][r];
            if (anym) {
#pragma unroll
                for (int ct = 0; ct < 4; ++ct) {
                    const unsigned int mb4 = *(const unsigned int*)&Ms[k0 + ct * 16 + quad * 4];
#pragma unroll
                    for (int r = 0; r < 4; ++r)
                        if ((mb4 >> (8 * r)) & 0xffu) sv[ct][r] = -1e30f;
                }
            }
            float mxv = sv[0][0];
#pragma unroll
            for (int ct = 0; ct < 4; ++ct)
#pragma unroll
                for (int r = 0; r < 4; ++r) mxv = fmaxf(mxv, sv[ct][r]);
            mxv = fmaxf(mxv, __shfl_xor(mxv, 16, 64));
            mxv = fmaxf(mxv, __shfl_xor(mxv, 32, 64));
            if (__any(mxv > m_r[u] + 8.0f)) {        // rare: real max growth
                const float mnew  = fmaxf(m_r[u], mxv);
                const float alpha = __expf(m_r[u] - mnew);
                l_r[u] *= alpha;
                m_r[u]  = mnew;
#pragma unroll
                for (int r = 0; r < 4; ++r) {
                    const float ar = __shfl(alpha, quad * 4 + r, 64);
#pragma unroll
                    for (int t = 0; t < 4; ++t) o[u][t][r] *= ar;
                }
            }
            float ls = 0.0f;
            bf16x4 w[4];
#pragma unroll
            for (int ct = 0; ct < 4; ++ct)
#pragma unroll
                for (int r = 0; r < 4; ++r) {
                    const float pv = __expf(sv[ct][r] - m_r[u]);   // bounded by e^8
                    ls += pv;
                    w[ct][r] = (__bf16)pv;
                }
            l_r[u] += ls;
#pragma unroll
            for (int ct = 0; ct < 4; ++ct)
                *(bf16x4*)&Ps[wave][u][l16 * 72 + ct * 16 + quad * 4] = w[ct];
        }
        // --- ONE wait, then a single 16-MFMA PV cluster ---
        asm volatile("s_waitcnt lgkmcnt(0)" ::: "memory");
        __builtin_amdgcn_sched_barrier(0);
        bf16x8 pa[2][2];
#pragma unroll
        for (int u = 0; u < 2; ++u) {
            pa[u][0] = ld8(&Ps[wave][u][l16 * 72 + quad * 8]);
            pa[u][1] = ld8(&Ps[wave][u][l16 * 72 + 32 + quad * 8]);
        }
        __builtin_amdgcn_s_setprio(1);
#pragma unroll
        for (int u = 0; u < 2; ++u)
#pragma unroll
            for (int t = 0; t < 4; ++t) {
                o[u][t] = __builtin_amdgcn_mfma_f32_16x16x32_bf16(pa[u][0], vf[t][0], o[u][t], 0, 0, 0);
                o[u][t] = __builtin_amdgcn_mfma_f32_16x16x32_bf16(pa[u][1], vf[t][1], o[u][t], 0, 0, 0);
            }
        __builtin_amdgcn_s_setprio(0);
        cur ^= 1;
    }
    // epilogue: reduce l across quads once, redistribute, normalize, gate, store
#pragma unroll
    for (int u = 0; u < 2; ++u) {
        float lt = l_r[u];
        lt += __shfl_xor(lt, 16, 64);
        lt += __shfl_xor(lt, 32, 64);
        const int rowg0 = b * 1024 + q0 + u * 16 + quad * 4;
#pragma unroll
        for (int r = 0; r < 4; ++r) {
            const float inv = 1.0f / __shfl(lt, quad * 4 + r, 64);
#pragma unroll
            for (int t = 0; t < 4; ++t) {
                const size_t idx = (size_t)(rowg0 + r) * Dm + h * 64 + t * 16 + l16;
                O[idx] = f2bf(o[u][t][r] * inv * bf2f(G[idx]));
            }
        }
    }
}

extern "C" void kernel_launch(void* const* d_in, const int* in_sizes, int n_in,
                              void* d_out, int out_size, void* d_ws, size_t ws_size,
                              hipStream_t stream)
{
    const void* query = d_in[0];
    const void* key   = d_in[1];
    const void* value = d_in[2];
    const void* Wq    = d_in[3];
    const void* bq    = d_in[4];
    const void* Wk    = d_in[5];
    const void* bk    = d_in[6];
    const void* Wv    = d_in[7];
    const void* bv    = d_in[8];
    const void* Wg    = d_in[9];
    const void* bg    = d_in[10];
    const void* Wo    = d_in[11];
    const void* bo    = d_in[12];
    const void* rc    = d_in[13];
    const void* rs    = d_in[14];
    const unsigned char* mask = (const unsigned char*)d_in[15];

    char* ws = (char*)d_ws;
    const size_t MB = (size_t)1 << 20;
    const size_t MB16 = 16 * MB;
    const bool big = ws_size >= 139 * MB;

    ushort* Qp = (ushort*)(ws);
    ushort* Kp = (ushort*)(ws + 1 * MB16);
    ushort* Vp = (ushort*)(ws + 2 * MB16);
    ushort* Gt = (ushort*)(ws + 3 * MB16);
    ushort* Vt = (ushort*)(ws + 4 * MB16);
    ushort* Ag = (ushort*)(ws + 2 * MB16);       // alias Vp: dead after transpose
    int*  flag = (int*)(ws + (big ? 138 * MB : 5 * MB16));

    const dim3 gb(512), gt(256);
    hipLaunchKernelGGL(sniff_kernel, dim3(1), dim3(64), 0, stream, (const ushort*)query, flag);

    if (big) {
        ushort* qbf = (ushort*)(ws + 80 * MB);
        ushort* kbf = (ushort*)(ws + 96 * MB);
        ushort* vbf = (ushort*)(ws + 112 * MB);
        ushort* wcat = (ushort*)(ws + 128 * MB); // wb[0..3] contiguous = Wcat[4096][1024]
        ushort* wb[5];
        for (int i = 0; i < 5; ++i) wb[i] = wcat + (size_t)i * 1024 * 1024;

        hipLaunchKernelGGL(cvt_qkv, dim3(3 * 2048), dim3(256), 0, stream,
                           query, key, value, qbf, kbf, vbf, flag);
        hipLaunchKernelGGL(cvt_w5, dim3(5 * 512), dim3(256), 0, stream,
                           Wq, Wk, Wv, Wg, Wo, wb[0], wb[1], wb[2], wb[3], wb[4], flag);

        hipLaunchKernelGGL(gemm_qkvg, dim3(2048), dim3(256), 0, stream,
                           qbf, kbf, vbf, wcat, bq, bk, bv, bg, rc, rs,
                           Qp, Kp, Vp, Gt, flag);

        hipLaunchKernelGGL(transpose_vh, dim3(2048), dim3(256), 0, stream, Vp, Vt);
        hipLaunchKernelGGL(attn_kernel,  dim3(512), dim3(512), 0, stream, Qp, Kp, Vt, Gt, mask, Ag);

        hipLaunchKernelGGL((gemm_bt<0,1,1,1>), gb, gt, 0, stream, Ag, wb[4], bo, rc, rs, d_out, flag);
    } else {
        hipLaunchKernelGGL((gemm_bt<3,0,0,0>), gb, gt, 0, stream, query, Wq, bq, rc, rs, Qp, flag);
        hipLaunchKernelGGL((gemm_bt<1,0,0,0>), gb, gt, 0, stream, key,   Wk, bk, rc, rs, Kp, flag);
        hipLaunchKernelGGL((gemm_bt<0,0,0,0>), gb, gt, 0, stream, value, Wv, bv, rc, rs, Vp, flag);
        hipLaunchKernelGGL((gemm_bt<2,0,0,0>), gb, gt, 0, stream, query, Wg, bg, rc, rs, Gt, flag);

        hipLaunchKernelGGL(transpose_vh, dim3(2048), dim3(256), 0, stream, Vp, Vt);
        hipLaunchKernelGGL(attn_kernel,  dim3(512), dim3(512), 0, stream, Qp, Kp, Vt, Gt, mask, Ag);

        hipLaunchKernelGGL((gemm_bt<0,1,0,1>), gb, gt, 0, stream, Ag, Wo, bo, rc, rs, d_out, flag);
    }
}